// Round 1
// baseline (272.352 us; speedup 1.0000x reference)
//
#include <hip/hip_runtime.h>

#define B_ 2
#define S_ 2048
#define D_ 1024
#define H_ 16
#define DH_ 64

typedef short v8s __attribute__((ext_vector_type(8)));
typedef float v4f __attribute__((ext_vector_type(4)));

__device__ inline short f2bf(float f) {
  unsigned u = __float_as_uint(f);
  u = (u + 0x7FFFu + ((u >> 16) & 1u)) >> 16;
  return (short)u;
}

// ---------------- fused causal flash attention -> z (bf16) ----------------
#define QBLK 64
#define KT 32

__global__ __launch_bounds__(256) void attn_kernel(
    const float* __restrict__ q, const float* __restrict__ k,
    const float* __restrict__ v, short* __restrict__ z) {
  const int nqt = S_ / QBLK;  // 32
  int bid = blockIdx.x;
  int qt = bid % nqt;
  int bh = bid / nqt;
  int b = bh / H_;
  int h = bh % H_;
  int tid = threadIdx.x;
  int wave = tid >> 6;
  int lane = tid & 63;
  int lh = lane >> 4;  // 0..3
  int ll = lane & 15;  // 0..15

  int qbase = qt * QBLK;
  int qrow0 = qbase + wave * 16;  // this wave's 16 query rows

  __shared__ short Klds[KT][DH_ + 8];       // [key][dim], stride 144B (16B-mult)
  __shared__ short Vlds[DH_][KT + 8];       // transposed: [dim][key], stride 80B
  __shared__ short Plds[4][16][KT + 8];     // per-wave P staging

  // Q fragments: lane holds Q[row=qrow0+ll][d = c*32 + lh*8 + j]
  v8s qf[2];
  {
    const float* qp = q + ((size_t)(b * S_ + qrow0 + ll)) * D_ + h * DH_;
    for (int c = 0; c < 2; ++c) {
      int d0 = c * 32 + lh * 8;
      float4 a = *(const float4*)(qp + d0);
      float4 bb = *(const float4*)(qp + d0 + 4);
      v8s t;
      t[0] = f2bf(a.x);  t[1] = f2bf(a.y);  t[2] = f2bf(a.z);  t[3] = f2bf(a.w);
      t[4] = f2bf(bb.x); t[5] = f2bf(bb.y); t[6] = f2bf(bb.z); t[7] = f2bf(bb.w);
      qf[c] = t;
    }
  }

  float M[4], L[4];
  v4f O[4];
  for (int r = 0; r < 4; ++r) { M[r] = -INFINITY; L[r] = 0.f; }
  for (int cb = 0; cb < 4; ++cb) O[cb] = (v4f){0.f, 0.f, 0.f, 0.f};

  const int ntiles = (qbase + QBLK) / KT;  // 2*qt + 2
  const int skey = tid >> 3;        // 0..31
  const int sd0 = (tid & 7) * 8;    // 0..56

  for (int kt = 0; kt < ntiles; ++kt) {
    int kb = kt * KT;
    __syncthreads();
    // stage K tile and transposed V tile
    {
      const float* kp = k + ((size_t)(b * S_ + kb + skey)) * D_ + h * DH_ + sd0;
      const float* vp = v + ((size_t)(b * S_ + kb + skey)) * D_ + h * DH_ + sd0;
      float4 a = *(const float4*)kp;
      float4 bb = *(const float4*)(kp + 4);
      v8s t;
      t[0] = f2bf(a.x);  t[1] = f2bf(a.y);  t[2] = f2bf(a.z);  t[3] = f2bf(a.w);
      t[4] = f2bf(bb.x); t[5] = f2bf(bb.y); t[6] = f2bf(bb.z); t[7] = f2bf(bb.w);
      *(v8s*)&Klds[skey][sd0] = t;
      a = *(const float4*)vp;
      bb = *(const float4*)(vp + 4);
      Vlds[sd0 + 0][skey] = f2bf(a.x);
      Vlds[sd0 + 1][skey] = f2bf(a.y);
      Vlds[sd0 + 2][skey] = f2bf(a.z);
      Vlds[sd0 + 3][skey] = f2bf(a.w);
      Vlds[sd0 + 4][skey] = f2bf(bb.x);
      Vlds[sd0 + 5][skey] = f2bf(bb.y);
      Vlds[sd0 + 6][skey] = f2bf(bb.z);
      Vlds[sd0 + 7][skey] = f2bf(bb.w);
    }
    __syncthreads();

    bool active = (kb <= qrow0 + 15);
    if (active) {
      // S = Q K^T : two 16x16 col-blocks of keys
      v4f sf[2];
      sf[0] = (v4f){0.f, 0.f, 0.f, 0.f};
      sf[1] = (v4f){0.f, 0.f, 0.f, 0.f};
      for (int cb = 0; cb < 2; ++cb)
        for (int c = 0; c < 2; ++c) {
          v8s kf = *(const v8s*)&Klds[cb * 16 + ll][c * 32 + lh * 8];
          sf[cb] = __builtin_amdgcn_mfma_f32_16x16x32_bf16(qf[c], kf, sf[cb], 0, 0, 0);
        }
      // scale + causal mask
      bool diag = (kb + KT > qrow0);
      for (int cb = 0; cb < 2; ++cb)
        for (int r = 0; r < 4; ++r) {
          float s = sf[cb][r] * 0.125f;
          if (diag) {
            int qr = qrow0 + lh * 4 + r;
            int kc = kb + cb * 16 + ll;
            if (kc > qr) s = -1e30f;
          }
          sf[cb][r] = s;
        }
      // online softmax (rows live across 16 lanes sharing lh)
      float pm[4];
      for (int r = 0; r < 4; ++r) {
        float m2 = fmaxf(sf[0][r], sf[1][r]);
        for (int off = 1; off < 16; off <<= 1)
          m2 = fmaxf(m2, __shfl_xor(m2, off, 64));
        pm[r] = m2;
      }
      float p0[4], p1[4], al[4];
      for (int r = 0; r < 4; ++r) {
        float Mn = fmaxf(M[r], pm[r]);
        al[r] = __expf(M[r] - Mn);
        p0[r] = __expf(sf[0][r] - Mn);
        p1[r] = __expf(sf[1][r] - Mn);
        float rs = p0[r] + p1[r];
        for (int off = 1; off < 16; off <<= 1)
          rs += __shfl_xor(rs, off, 64);
        L[r] = L[r] * al[r] + rs;
        M[r] = Mn;
      }
      for (int cb = 0; cb < 4; ++cb)
        for (int r = 0; r < 4; ++r) O[cb][r] *= al[r];
      // stage P (C-layout -> A-frag layout) through per-wave LDS
      for (int r = 0; r < 4; ++r) {
        Plds[wave][lh * 4 + r][ll] = f2bf(p0[r]);
        Plds[wave][lh * 4 + r][16 + ll] = f2bf(p1[r]);
      }
      v8s pa = *(const v8s*)&Plds[wave][ll][lh * 8];
      for (int cb = 0; cb < 4; ++cb) {
        v8s vf = *(const v8s*)&Vlds[cb * 16 + ll][lh * 8];
        O[cb] = __builtin_amdgcn_mfma_f32_16x16x32_bf16(pa, vf, O[cb], 0, 0, 0);
      }
    }
  }

  // epilogue: z[b*S+row][h*64 + d] = O/L  (bf16)
  for (int r = 0; r < 4; ++r) {
    float inv = 1.f / L[r];
    int row = qrow0 + lh * 4 + r;
    size_t base = ((size_t)(b * S_ + row)) * (size_t)D_ + h * DH_;
    for (int cb = 0; cb < 4; ++cb)
      z[base + cb * 16 + ll] = f2bf(O[cb][r] * inv);
  }
}

// ---------------- projection GEMM: out = z @ W + b ----------------
#define BM 128
#define BN 128
#define BK 32

__global__ __launch_bounds__(256) void proj_kernel(
    const short* __restrict__ z, const float* __restrict__ W,
    const float* __restrict__ bias, float* __restrict__ out) {
  int bm = blockIdx.x;  // 0..31
  int bn = blockIdx.y;  // 0..7
  int tid = threadIdx.x;
  int wave = tid >> 6, lane = tid & 63, lh = lane >> 4, ll = lane & 15;
  int wr = wave >> 1, wc = wave & 1;

  __shared__ short Alds[BM][BK + 8];  // [row][k]
  __shared__ short Blds[BN][BK + 8];  // transposed: [col][k]

  v4f acc[4][4];
  for (int m = 0; m < 4; ++m)
    for (int n = 0; n < 4; ++n) acc[m][n] = (v4f){0.f, 0.f, 0.f, 0.f};

  const int arow = tid >> 1, ak = (tid & 1) * 16;
  const int bk = tid >> 3, bc0 = (tid & 7) * 16;

  for (int kt = 0; kt < D_ / BK; ++kt) {
    int kb = kt * BK;
    __syncthreads();
    {
      const short* ap = z + (size_t)(bm * BM + arow) * D_ + kb + ak;
      v8s t0 = *(const v8s*)ap;
      v8s t1 = *(const v8s*)(ap + 8);
      *(v8s*)&Alds[arow][ak] = t0;
      *(v8s*)&Alds[arow][ak + 8] = t1;
    }
    {
      const float* wp = W + (size_t)(kb + bk) * D_ + bn * BN + bc0;
      for (int i = 0; i < 16; i += 4) {
        float4 a = *(const float4*)(wp + i);
        Blds[bc0 + i + 0][bk] = f2bf(a.x);
        Blds[bc0 + i + 1][bk] = f2bf(a.y);
        Blds[bc0 + i + 2][bk] = f2bf(a.z);
        Blds[bc0 + i + 3][bk] = f2bf(a.w);
      }
    }
    __syncthreads();
    v8s af[4], bf[4];
    for (int m = 0; m < 4; ++m)
      af[m] = *(const v8s*)&Alds[wr * 64 + m * 16 + ll][lh * 8];
    for (int n = 0; n < 4; ++n)
      bf[n] = *(const v8s*)&Blds[wc * 64 + n * 16 + ll][lh * 8];
    for (int m = 0; m < 4; ++m)
      for (int n = 0; n < 4; ++n)
        acc[m][n] = __builtin_amdgcn_mfma_f32_16x16x32_bf16(af[m], bf[n], acc[m][n], 0, 0, 0);
  }

  for (int m = 0; m < 4; ++m) {
    int gr = bm * BM + wr * 64 + m * 16 + lh * 4;
    for (int n = 0; n < 4; ++n) {
      int gc = bn * BN + wc * 64 + n * 16 + ll;
      float bo = bias[gc];
      for (int r = 0; r < 4; ++r)
        out[(size_t)(gr + r) * D_ + gc] = acc[m][n][r] + bo;
    }
  }
}

extern "C" void kernel_launch(void* const* d_in, const int* in_sizes, int n_in,
                              void* d_out, int out_size, void* d_ws, size_t ws_size,
                              hipStream_t stream) {
  const float* residual = (const float*)d_in[0];
  const float* q = (const float*)d_in[1];
  const float* k = (const float*)d_in[2];
  const float* v = (const float*)d_in[3];
  const float* W = (const float*)d_in[4];
  const float* bO = (const float*)d_in[5];
  float* out = (float*)d_out;
  short* z = (short*)d_ws;  // bf16 z: [B*S][H*DH] = 4096x1024, 8 MB

  const size_t half = (size_t)B_ * S_ * D_;

  // output 0: residual pass-through (exact)
  hipMemcpyAsync(out, residual, half * sizeof(float), hipMemcpyDeviceToDevice, stream);

  attn_kernel<<<dim3(B_ * H_ * (S_ / QBLK)), 256, 0, stream>>>(q, k, v, z);

  proj_kernel<<<dim3((B_ * S_) / BM, D_ / BN), 256, 0, stream>>>(z, W, bO, out + half);
}

// Round 2
// 172.616 us; speedup vs baseline: 1.5778x; 1.5778x over previous
//
#include <hip/hip_runtime.h>

#define B_ 2
#define S_ 2048
#define D_ 1024
#define H_ 16
#define DH_ 64

typedef short v8s __attribute__((ext_vector_type(8)));
typedef float v4f __attribute__((ext_vector_type(4)));

__device__ inline short f2bf(float f) {
  unsigned u = __float_as_uint(f);
  u = (u + 0x7FFFu + ((u >> 16) & 1u)) >> 16;
  return (short)u;
}

// ---------------- pre-convert kernels ----------------
__global__ __launch_bounds__(256) void cvt_bf16_kernel(const float* __restrict__ in,
                                                       short* __restrict__ out) {
  int i = blockIdx.x * blockDim.x + threadIdx.x;
  float4 a = ((const float4*)in)[2 * i];
  float4 b = ((const float4*)in)[2 * i + 1];
  v8s t;
  t[0] = f2bf(a.x); t[1] = f2bf(a.y); t[2] = f2bf(a.z); t[3] = f2bf(a.w);
  t[4] = f2bf(b.x); t[5] = f2bf(b.y); t[6] = f2bf(b.z); t[7] = f2bf(b.w);
  ((v8s*)out)[i] = t;
}

// v [b][s][h*64+d] f32 -> vt [(b*H+h)*64+d][s] bf16
__global__ __launch_bounds__(256) void cvt_vt_kernel(const float* __restrict__ v,
                                                     short* __restrict__ vt) {
  int bid = blockIdx.x;
  int st = bid & 31;        // S/64
  int bh = bid >> 5;
  int b = bh >> 4, h = bh & 15;
  int tid = threadIdx.x;
  __shared__ short t[64][64 + 8];
  int r = tid >> 2, c16 = (tid & 3) * 16;
  const float* vp = v + ((size_t)(b * S_ + st * 64 + r)) * D_ + h * DH_ + c16;
  for (int i = 0; i < 16; i += 4) {
    float4 a = *(const float4*)(vp + i);
    t[r][c16 + i + 0] = f2bf(a.x);
    t[r][c16 + i + 1] = f2bf(a.y);
    t[r][c16 + i + 2] = f2bf(a.z);
    t[r][c16 + i + 3] = f2bf(a.w);
  }
  __syncthreads();
  short* op = vt + ((size_t)((b * H_ + h) * DH_ + r)) * S_ + st * 64 + c16;
  v8s o0, o1;
  for (int j = 0; j < 8; ++j) { o0[j] = t[c16 + j][r]; o1[j] = t[c16 + 8 + j][r]; }
  *(v8s*)op = o0;
  *(v8s*)(op + 8) = o1;
}

// W [k][m] f32 (k = h*64+d, 1024x1024) -> wt [m][k] bf16
__global__ __launch_bounds__(256) void cvt_wt_kernel(const float* __restrict__ w,
                                                     short* __restrict__ wt) {
  int bid = blockIdx.x;
  int tk = bid & 15, tm = bid >> 4;
  int tid = threadIdx.x;
  __shared__ short t[64][64 + 8];
  int r = tid >> 2, c16 = (tid & 3) * 16;
  const float* wp = w + (size_t)(tk * 64 + r) * D_ + tm * 64 + c16;
  for (int i = 0; i < 16; i += 4) {
    float4 a = *(const float4*)(wp + i);
    t[r][c16 + i + 0] = f2bf(a.x);
    t[r][c16 + i + 1] = f2bf(a.y);
    t[r][c16 + i + 2] = f2bf(a.z);
    t[r][c16 + i + 3] = f2bf(a.w);
  }
  __syncthreads();
  short* op = wt + (size_t)(tm * 64 + r) * D_ + tk * 64 + c16;
  v8s o0, o1;
  for (int j = 0; j < 8; ++j) { o0[j] = t[c16 + j][r]; o1[j] = t[c16 + 8 + j][r]; }
  *(v8s*)op = o0;
  *(v8s*)(op + 8) = o1;
}

// ---------------- fused causal flash attention -> z (bf16) ----------------
#define QBLK 64
#define KT 64

// MODE 0: qv/kv/vv are f32 [b][s][h*64+d]
// MODE 1: qv/kv bf16 [b][s][h*64+d], vv bf16 [(b*H+h)*64+d][s]
template <int MODE>
__global__ __launch_bounds__(256) void attn_kernel(
    const void* __restrict__ qv, const void* __restrict__ kv,
    const void* __restrict__ vv, short* __restrict__ z) {
  const int nqt = S_ / QBLK;  // 32
  int bid = blockIdx.x;
  int qt = bid % nqt;
  int bh = bid / nqt;
  int b = bh / H_, h = bh % H_;
  int tid = threadIdx.x;
  int wave = tid >> 6, lane = tid & 63, lh = lane >> 4, ll = lane & 15;
  int qbase = qt * QBLK;
  int qrow0 = qbase + wave * 16;

  __shared__ short Klds[KT][DH_ + 8];    // [key][dim]
  __shared__ short Vlds[DH_][KT + 8];    // [dim][key]
  __shared__ short Plds[4][16][KT + 8];  // per-wave P staging

  v8s qf[2];
  if constexpr (MODE == 1) {
    const short* qp = (const short*)qv + ((size_t)(b * S_ + qrow0 + ll)) * D_ + h * DH_;
    qf[0] = *(const v8s*)(qp + lh * 8);
    qf[1] = *(const v8s*)(qp + 32 + lh * 8);
  } else {
    const float* qp = (const float*)qv + ((size_t)(b * S_ + qrow0 + ll)) * D_ + h * DH_;
    for (int c = 0; c < 2; ++c) {
      float4 a = *(const float4*)(qp + c * 32 + lh * 8);
      float4 bb = *(const float4*)(qp + c * 32 + lh * 8 + 4);
      v8s t;
      t[0] = f2bf(a.x);  t[1] = f2bf(a.y);  t[2] = f2bf(a.z);  t[3] = f2bf(a.w);
      t[4] = f2bf(bb.x); t[5] = f2bf(bb.y); t[6] = f2bf(bb.z); t[7] = f2bf(bb.w);
      qf[c] = t;
    }
  }

  float M[4], L[4];
  v4f O[4];
  for (int r = 0; r < 4; ++r) { M[r] = -INFINITY; L[r] = 0.f; }
  for (int cb = 0; cb < 4; ++cb) O[cb] = (v4f){0.f, 0.f, 0.f, 0.f};

  const int srow = tid >> 2;
  const int sc = (tid & 3) * 16;
  const int ntiles = qt + 1;

  for (int kt = 0; kt < ntiles; ++kt) {
    int kb = kt * KT;
    __syncthreads();
    if constexpr (MODE == 1) {
      const short* kp = (const short*)kv + ((size_t)(b * S_ + kb + srow)) * D_ + h * DH_ + sc;
      *(v8s*)&Klds[srow][sc] = *(const v8s*)kp;
      *(v8s*)&Klds[srow][sc + 8] = *(const v8s*)(kp + 8);
      const short* vp = (const short*)vv + ((size_t)((b * H_ + h) * DH_ + srow)) * S_ + kb + sc;
      *(v8s*)&Vlds[srow][sc] = *(const v8s*)vp;
      *(v8s*)&Vlds[srow][sc + 8] = *(const v8s*)(vp + 8);
    } else {
      const float* kp = (const float*)kv + ((size_t)(b * S_ + kb + srow)) * D_ + h * DH_ + sc;
      for (int i = 0; i < 16; i += 4) {
        float4 a = *(const float4*)(kp + i);
        Klds[srow][sc + i + 0] = f2bf(a.x);
        Klds[srow][sc + i + 1] = f2bf(a.y);
        Klds[srow][sc + i + 2] = f2bf(a.z);
        Klds[srow][sc + i + 3] = f2bf(a.w);
      }
      const float* vp = (const float*)vv + ((size_t)(b * S_ + kb + srow)) * D_ + h * DH_ + sc;
      for (int i = 0; i < 16; i += 4) {
        float4 a = *(const float4*)(vp + i);
        Vlds[sc + i + 0][srow] = f2bf(a.x);
        Vlds[sc + i + 1][srow] = f2bf(a.y);
        Vlds[sc + i + 2][srow] = f2bf(a.z);
        Vlds[sc + i + 3][srow] = f2bf(a.w);
      }
    }
    __syncthreads();

    // S = Q K^T : four 16-key col-blocks
    v4f sf[4];
    for (int cb = 0; cb < 4; ++cb) sf[cb] = (v4f){0.f, 0.f, 0.f, 0.f};
    for (int cb = 0; cb < 4; ++cb)
      for (int c = 0; c < 2; ++c) {
        v8s kf = *(const v8s*)&Klds[cb * 16 + ll][c * 32 + lh * 8];
        sf[cb] = __builtin_amdgcn_mfma_f32_16x16x32_bf16(qf[c], kf, sf[cb], 0, 0, 0);
      }
    bool diag = (kb + KT > qrow0);
    for (int cb = 0; cb < 4; ++cb)
      for (int r = 0; r < 4; ++r) {
        float s = sf[cb][r] * 0.125f;
        if (diag && (kb + cb * 16 + ll > qrow0 + lh * 4 + r)) s = -1e30f;
        sf[cb][r] = s;
      }
    float p[4][4];
    for (int r = 0; r < 4; ++r) {
      float m2 = fmaxf(fmaxf(sf[0][r], sf[1][r]), fmaxf(sf[2][r], sf[3][r]));
      for (int off = 1; off < 16; off <<= 1) m2 = fmaxf(m2, __shfl_xor(m2, off));
      float Mn = fmaxf(M[r], m2);
      float al = __expf(M[r] - Mn);
      float rs = 0.f;
      for (int cb = 0; cb < 4; ++cb) { p[cb][r] = __expf(sf[cb][r] - Mn); rs += p[cb][r]; }
      for (int off = 1; off < 16; off <<= 1) rs += __shfl_xor(rs, off);
      L[r] = L[r] * al + rs;
      M[r] = Mn;
      for (int cb = 0; cb < 4; ++cb) O[cb][r] *= al;
    }
    for (int r = 0; r < 4; ++r)
      for (int cb = 0; cb < 4; ++cb)
        Plds[wave][lh * 4 + r][cb * 16 + ll] = f2bf(p[cb][r]);
    v8s pa0 = *(const v8s*)&Plds[wave][ll][lh * 8];
    v8s pa1 = *(const v8s*)&Plds[wave][ll][32 + lh * 8];
    for (int cb = 0; cb < 4; ++cb) {
      v8s vf0 = *(const v8s*)&Vlds[cb * 16 + ll][lh * 8];
      O[cb] = __builtin_amdgcn_mfma_f32_16x16x32_bf16(pa0, vf0, O[cb], 0, 0, 0);
      v8s vf1 = *(const v8s*)&Vlds[cb * 16 + ll][32 + lh * 8];
      O[cb] = __builtin_amdgcn_mfma_f32_16x16x32_bf16(pa1, vf1, O[cb], 0, 0, 0);
    }
  }

  for (int r = 0; r < 4; ++r) {
    float inv = 1.f / L[r];
    int row = qrow0 + lh * 4 + r;
    size_t base = ((size_t)(b * S_ + row)) * (size_t)D_ + h * DH_;
    for (int cb = 0; cb < 4; ++cb)
      z[base + cb * 16 + ll] = f2bf(O[cb][r] * inv);
  }
}

// ---------------- projection GEMM: out = z @ W + b ----------------
#define BM 128
#define BN 128
#define BK 32

// MODE 0: w = f32 W [k][m]; MODE 1: w = bf16 Wt [m][k]
template <int MODE>
__global__ __launch_bounds__(256) void proj_kernel(
    const short* __restrict__ z, const void* __restrict__ w,
    const float* __restrict__ bias, float* __restrict__ out) {
  int bm = blockIdx.x;
  int bn = blockIdx.y;
  int tid = threadIdx.x;
  int wave = tid >> 6, lane = tid & 63, lh = lane >> 4, ll = lane & 15;
  int wr = wave >> 1, wc = wave & 1;

  __shared__ short Alds[BM][BK + 8];
  __shared__ short Blds[BN][BK + 8];

  v4f acc[4][4];
  for (int m = 0; m < 4; ++m)
    for (int n = 0; n < 4; ++n) acc[m][n] = (v4f){0.f, 0.f, 0.f, 0.f};

  for (int kt = 0; kt < D_ / BK; ++kt) {
    int kb = kt * BK;
    __syncthreads();
    {
      const short* ap = z + (size_t)(bm * BM + (tid >> 1)) * D_ + kb + (tid & 1) * 16;
      *(v8s*)&Alds[tid >> 1][(tid & 1) * 16] = *(const v8s*)ap;
      *(v8s*)&Alds[tid >> 1][(tid & 1) * 16 + 8] = *(const v8s*)(ap + 8);
    }
    if constexpr (MODE == 1) {
      const short* wp = (const short*)w + (size_t)(bn * BN + (tid >> 1)) * D_ + kb + (tid & 1) * 16;
      *(v8s*)&Blds[tid >> 1][(tid & 1) * 16] = *(const v8s*)wp;
      *(v8s*)&Blds[tid >> 1][(tid & 1) * 16 + 8] = *(const v8s*)(wp + 8);
    } else {
      int bk = tid >> 3, bc0 = (tid & 7) * 16;
      const float* wp = (const float*)w + (size_t)(kb + bk) * D_ + bn * BN + bc0;
      for (int i = 0; i < 16; i += 4) {
        float4 a = *(const float4*)(wp + i);
        Blds[bc0 + i + 0][bk] = f2bf(a.x);
        Blds[bc0 + i + 1][bk] = f2bf(a.y);
        Blds[bc0 + i + 2][bk] = f2bf(a.z);
        Blds[bc0 + i + 3][bk] = f2bf(a.w);
      }
    }
    __syncthreads();
    v8s af[4], bf[4];
    for (int m = 0; m < 4; ++m)
      af[m] = *(const v8s*)&Alds[wr * 64 + m * 16 + ll][lh * 8];
    for (int n = 0; n < 4; ++n)
      bf[n] = *(const v8s*)&Blds[wc * 64 + n * 16 + ll][lh * 8];
    for (int m = 0; m < 4; ++m)
      for (int n = 0; n < 4; ++n)
        acc[m][n] = __builtin_amdgcn_mfma_f32_16x16x32_bf16(af[m], bf[n], acc[m][n], 0, 0, 0);
  }

  for (int m = 0; m < 4; ++m) {
    int gr = bm * BM + wr * 64 + m * 16 + lh * 4;
    for (int n = 0; n < 4; ++n) {
      int gc = bn * BN + wc * 64 + n * 16 + ll;
      float bo = bias[gc];
      for (int r = 0; r < 4; ++r)
        out[(size_t)(gr + r) * D_ + gc] = acc[m][n][r] + bo;
    }
  }
}

extern "C" void kernel_launch(void* const* d_in, const int* in_sizes, int n_in,
                              void* d_out, int out_size, void* d_ws, size_t ws_size,
                              hipStream_t stream) {
  const float* residual = (const float*)d_in[0];
  const float* q = (const float*)d_in[1];
  const float* k = (const float*)d_in[2];
  const float* v = (const float*)d_in[3];
  const float* W = (const float*)d_in[4];
  const float* bO = (const float*)d_in[5];
  float* out = (float*)d_out;

  const size_t half = (size_t)B_ * S_ * D_;  // 4194304 elements
  short* z = (short*)d_ws;
  const size_t need = half * 2 * 4 + (size_t)D_ * D_ * 2;  // z+qb+kb+vt+wt bytes

  // output 0: residual pass-through (exact)
  hipMemcpyAsync(out, residual, half * sizeof(float), hipMemcpyDeviceToDevice, stream);

  if (ws_size >= need) {
    short* qb = z + half;
    short* kb = qb + half;
    short* vt = kb + half;
    short* wt = vt + half;
    cvt_bf16_kernel<<<half / 2048, 256, 0, stream>>>(q, qb);
    cvt_bf16_kernel<<<half / 2048, 256, 0, stream>>>(k, kb);
    cvt_vt_kernel<<<B_ * H_ * (S_ / 64), 256, 0, stream>>>(v, vt);
    cvt_wt_kernel<<<(D_ / 64) * (D_ / 64), 256, 0, stream>>>(W, wt);
    attn_kernel<1><<<B_ * H_ * (S_ / QBLK), 256, 0, stream>>>(qb, kb, vt, z);
    proj_kernel<1><<<dim3((B_ * S_) / BM, D_ / BN), 256, 0, stream>>>(z, wt, bO, out + half);
  } else {
    attn_kernel<0><<<B_ * H_ * (S_ / QBLK), 256, 0, stream>>>(q, k, v, z);
    proj_kernel<0><<<dim3((B_ * S_) / BM, D_ / BN), 256, 0, stream>>>(z, W, bO, out + half);
  }
}

// Round 3
// 132.213 us; speedup vs baseline: 2.0599x; 1.3056x over previous
//
#include <hip/hip_runtime.h>

#define B_ 2
#define S_ 2048
#define D_ 1024
#define H_ 16
#define DH_ 64

typedef short v4s __attribute__((ext_vector_type(4)));
typedef short v8s __attribute__((ext_vector_type(8)));
typedef float v4f __attribute__((ext_vector_type(4)));

__device__ inline short f2bf(float f) {
  unsigned u = __float_as_uint(f);
  u = (u + 0x7FFFu + ((u >> 16) & 1u)) >> 16;
  return (short)u;
}

__device__ inline void gll16(const void* g, void* l) {
  __builtin_amdgcn_global_load_lds(
      (const __attribute__((address_space(1))) void*)g,
      (__attribute__((address_space(3))) void*)l, 16, 0, 0);
}

// ---------------- pre-convert kernels ----------------
__global__ __launch_bounds__(256) void cvt_bf16_kernel(const float* __restrict__ in,
                                                       short* __restrict__ out) {
  int i = blockIdx.x * blockDim.x + threadIdx.x;
  float4 a = ((const float4*)in)[2 * i];
  float4 b = ((const float4*)in)[2 * i + 1];
  v8s t;
  t[0] = f2bf(a.x); t[1] = f2bf(a.y); t[2] = f2bf(a.z); t[3] = f2bf(a.w);
  t[4] = f2bf(b.x); t[5] = f2bf(b.y); t[6] = f2bf(b.z); t[7] = f2bf(b.w);
  ((v8s*)out)[i] = t;
}

// v [b][s][h*64+d] f32 -> vt [(b*H+h)*64+d][s] bf16
__global__ __launch_bounds__(256) void cvt_vt_kernel(const float* __restrict__ v,
                                                     short* __restrict__ vt) {
  int bid = blockIdx.x;
  int st = bid & 31;
  int bh = bid >> 5;
  int b = bh >> 4, h = bh & 15;
  int tid = threadIdx.x;
  __shared__ short t[64][64 + 8];
  int r = tid >> 2, c16 = (tid & 3) * 16;
  const float* vp = v + ((size_t)(b * S_ + st * 64 + r)) * D_ + h * DH_ + c16;
  for (int i = 0; i < 16; i += 4) {
    float4 a = *(const float4*)(vp + i);
    t[r][c16 + i + 0] = f2bf(a.x);
    t[r][c16 + i + 1] = f2bf(a.y);
    t[r][c16 + i + 2] = f2bf(a.z);
    t[r][c16 + i + 3] = f2bf(a.w);
  }
  __syncthreads();
  short* op = vt + ((size_t)((b * H_ + h) * DH_ + r)) * S_ + st * 64 + c16;
  v8s o0, o1;
  for (int j = 0; j < 8; ++j) { o0[j] = t[c16 + j][r]; o1[j] = t[c16 + 8 + j][r]; }
  *(v8s*)op = o0;
  *(v8s*)(op + 8) = o1;
}

// W [k][m] f32 -> wt [m][k] bf16
__global__ __launch_bounds__(256) void cvt_wt_kernel(const float* __restrict__ w,
                                                     short* __restrict__ wt) {
  int bid = blockIdx.x;
  int tk = bid & 15, tm = bid >> 4;
  int tid = threadIdx.x;
  __shared__ short t[64][64 + 8];
  int r = tid >> 2, c16 = (tid & 3) * 16;
  const float* wp = w + (size_t)(tk * 64 + r) * D_ + tm * 64 + c16;
  for (int i = 0; i < 16; i += 4) {
    float4 a = *(const float4*)(wp + i);
    t[r][c16 + i + 0] = f2bf(a.x);
    t[r][c16 + i + 1] = f2bf(a.y);
    t[r][c16 + i + 2] = f2bf(a.z);
    t[r][c16 + i + 3] = f2bf(a.w);
  }
  __syncthreads();
  short* op = wt + (size_t)(tm * 64 + r) * D_ + tk * 64 + c16;
  v8s o0, o1;
  for (int j = 0; j < 8; ++j) { o0[j] = t[c16 + j][r]; o1[j] = t[c16 + 8 + j][r]; }
  *(v8s*)op = o0;
  *(v8s*)(op + 8) = o1;
}

// ---------------- fused causal flash attention -> z (bf16) ----------------
// 256 blocks; block = (bh, pair). Each block: q-tiles qtA=pair, qtB=15-pair
// (128 rows each) -> exactly 34 K-tiles of 64 per block. 4 waves x 32 q-rows.
// Swapped QK^T: lane holds P[k][q=ll] in regs -> in-register softmax.
#define KT 64

__global__ __launch_bounds__(256) void attn_kernel(
    const float* __restrict__ q, const short* __restrict__ kbf,
    const short* __restrict__ vtb, short* __restrict__ z) {
  int bid = blockIdx.x;
  int pair = bid & 7;
  int bh = bid >> 3;
  int b = bh >> 4, h = bh & 15;
  int tid = threadIdx.x;
  int wave = tid >> 6, lane = tid & 63, lh = lane >> 4, ll = lane & 15;

  __shared__ short Klds[2][KT][64];   // [key][d], XOR-swizzled cols
  __shared__ short Vlds[2][DH_][64];  // [d][key], XOR-swizzled cols
  __shared__ short Plds[4][32][72];   // per-wave P^T staging [q][k]

  const int qtA = pair, qtB = 15 - pair;
  const int nA = 2 * qtA + 2;
  const int nTot = nA + 2 * qtB + 2;  // == 34

  const int r8 = lane >> 3;
  const int scol = ((lane & 7) ^ r8) << 3;  // pre-swizzled source col (shorts)

  const short* kbase = kbf + (size_t)b * S_ * D_ + h * DH_;
  const short* vbase = vtb + ((size_t)(b * H_ + h) * DH_) * S_;

  int qbase = qtA * 128;
  float M[2] = {-INFINITY, -INFINITY}, L[2] = {0.f, 0.f};
  v4f O[2][4];
#pragma unroll
  for (int qs = 0; qs < 2; ++qs)
#pragma unroll
    for (int dblk = 0; dblk < 4; ++dblk) O[qs][dblk] = (v4f){0.f, 0.f, 0.f, 0.f};

  v8s qf[2][2];
  {
    const float* qp = q + (size_t)(b * S_ + qbase + wave * 32 + ll) * D_ + h * DH_;
#pragma unroll
    for (int qs = 0; qs < 2; ++qs)
#pragma unroll
      for (int c = 0; c < 2; ++c) {
        const float* pp = qp + qs * 16 * D_ + c * 32 + lh * 8;
        float4 x = *(const float4*)pp;
        float4 y = *(const float4*)(pp + 4);
        v8s t;
        t[0] = f2bf(x.x); t[1] = f2bf(x.y); t[2] = f2bf(x.z); t[3] = f2bf(x.w);
        t[4] = f2bf(y.x); t[5] = f2bf(y.y); t[6] = f2bf(y.z); t[7] = f2bf(y.w);
        qf[qs][c] = t;
      }
  }

  auto stage = [&](int kb, int bbuf) {
#pragma unroll
    for (int i = 0; i < 2; ++i) {
      int c = wave * 2 + i;
      gll16(kbase + (size_t)(kb + c * 8 + r8) * D_ + scol, &Klds[bbuf][c * 8][0]);
      gll16(vbase + (size_t)(c * 8 + r8) * S_ + kb + scol, &Vlds[bbuf][c * 8][0]);
    }
  };

  stage(0, 0);
  __syncthreads();

  for (int s = 0; s < nTot; ++s) {
    int kb = (s < nA ? s : s - nA) * KT;
    int bbf = s & 1;
    if (s + 1 < nTot) {
      int s2 = s + 1;
      stage((s2 < nA ? s2 : s2 - nA) * KT, bbf ^ 1);
    }

    // QK^T swapped: sf[qs][cb] = S^T[k = kb+cb*16+lh*4+r][q = qs-block row ll]
    v4f sf[2][4];
#pragma unroll
    for (int qs = 0; qs < 2; ++qs)
#pragma unroll
      for (int cb = 0; cb < 4; ++cb) sf[qs][cb] = (v4f){0.f, 0.f, 0.f, 0.f};
#pragma unroll
    for (int cb = 0; cb < 4; ++cb) {
      int krow = cb * 16 + ll;
#pragma unroll
      for (int c = 0; c < 2; ++c) {
        v8s kf = *(const v8s*)&Klds[bbf][krow][(((c << 2) | lh) ^ (ll & 7)) << 3];
        sf[0][cb] = __builtin_amdgcn_mfma_f32_16x16x32_bf16(kf, qf[0][c], sf[0][cb], 0, 0, 0);
        sf[1][cb] = __builtin_amdgcn_mfma_f32_16x16x32_bf16(kf, qf[1][c], sf[1][cb], 0, 0, 0);
      }
    }

#pragma unroll
    for (int qs = 0; qs < 2; ++qs) {
      int gmin = qbase + wave * 32 + qs * 16;
      int qg = gmin + ll;
      bool msk = (kb + 63 > gmin);
      float p[4][4];
      float pmax = -3.0e38f;
#pragma unroll
      for (int cb = 0; cb < 4; ++cb)
#pragma unroll
        for (int r = 0; r < 4; ++r) {
          float sv = sf[qs][cb][r] * 0.125f;
          if (msk && (kb + cb * 16 + lh * 4 + r > qg)) sv = -1e30f;
          p[cb][r] = sv;
          pmax = fmaxf(pmax, sv);
        }
      pmax = fmaxf(pmax, __shfl_xor(pmax, 16));
      pmax = fmaxf(pmax, __shfl_xor(pmax, 32));
      float Mn = fmaxf(M[qs], pmax);
      float al = __expf(M[qs] - Mn);
      float rs = 0.f;
#pragma unroll
      for (int cb = 0; cb < 4; ++cb)
#pragma unroll
        for (int r = 0; r < 4; ++r) {
          float e = __expf(p[cb][r] - Mn);
          p[cb][r] = e;
          rs += e;
        }
      rs += __shfl_xor(rs, 16);
      rs += __shfl_xor(rs, 32);
      L[qs] = L[qs] * al + rs;
      M[qs] = Mn;
#pragma unroll
      for (int dblk = 0; dblk < 4; ++dblk)
#pragma unroll
        for (int r = 0; r < 4; ++r) O[qs][dblk][r] *= al;
#pragma unroll
      for (int cb = 0; cb < 4; ++cb) {
        v4s pk;
#pragma unroll
        for (int r = 0; r < 4; ++r) pk[r] = f2bf(p[cb][r]);
        *(v4s*)&Plds[wave][qs * 16 + ll][cb * 16 + lh * 4] = pk;
      }
    }

    v8s pb0[2], pb1[2];
#pragma unroll
    for (int kh = 0; kh < 2; ++kh) {
      pb0[kh] = *(const v8s*)&Plds[wave][ll][kh * 32 + lh * 8];
      pb1[kh] = *(const v8s*)&Plds[wave][16 + ll][kh * 32 + lh * 8];
    }
#pragma unroll
    for (int dblk = 0; dblk < 4; ++dblk) {
      int drow = dblk * 16 + ll;
#pragma unroll
      for (int kh = 0; kh < 2; ++kh) {
        v8s vf = *(const v8s*)&Vlds[bbf][drow][(((kh << 2) | lh) ^ (ll & 7)) << 3];
        O[0][dblk] = __builtin_amdgcn_mfma_f32_16x16x32_bf16(vf, pb0[kh], O[0][dblk], 0, 0, 0);
        O[1][dblk] = __builtin_amdgcn_mfma_f32_16x16x32_bf16(vf, pb1[kh], O[1][dblk], 0, 0, 0);
      }
    }

    if (s == nA - 1 || s == nTot - 1) {
#pragma unroll
      for (int qs = 0; qs < 2; ++qs) {
        float inv = 1.f / L[qs];
        int qg = qbase + wave * 32 + qs * 16 + ll;
        short* zp = z + (size_t)(b * S_ + qg) * D_ + h * DH_;
#pragma unroll
        for (int dblk = 0; dblk < 4; ++dblk) {
          v4s o;
#pragma unroll
          for (int r = 0; r < 4; ++r) o[r] = f2bf(O[qs][dblk][r] * inv);
          *(v4s*)&zp[dblk * 16 + lh * 4] = o;
        }
      }
      if (s == nA - 1) {
        qbase = qtB * 128;
        const float* qp = q + (size_t)(b * S_ + qbase + wave * 32 + ll) * D_ + h * DH_;
#pragma unroll
        for (int qs = 0; qs < 2; ++qs) {
          M[qs] = -INFINITY;
          L[qs] = 0.f;
#pragma unroll
          for (int dblk = 0; dblk < 4; ++dblk) O[qs][dblk] = (v4f){0.f, 0.f, 0.f, 0.f};
#pragma unroll
          for (int c = 0; c < 2; ++c) {
            const float* pp = qp + qs * 16 * D_ + c * 32 + lh * 8;
            float4 x = *(const float4*)pp;
            float4 y = *(const float4*)(pp + 4);
            v8s t;
            t[0] = f2bf(x.x); t[1] = f2bf(x.y); t[2] = f2bf(x.z); t[3] = f2bf(x.w);
            t[4] = f2bf(y.x); t[5] = f2bf(y.y); t[6] = f2bf(y.z); t[7] = f2bf(y.w);
            qf[qs][c] = t;
          }
        }
      }
    }
    __syncthreads();
  }
}

// ---------------- projection GEMM: out = z @ Wt^T + b ----------------
// BM=64, BN=128, BK=64, 512 blocks (2/CU), dbuf + global_load_lds + swizzle.
__global__ __launch_bounds__(256) void proj_kernel(
    const short* __restrict__ z, const short* __restrict__ wt,
    const float* __restrict__ bias, float* __restrict__ out) {
  int bm = blockIdx.x, bn = blockIdx.y;
  int tid = threadIdx.x;
  int wave = tid >> 6, lane = tid & 63, lh = lane >> 4, ll = lane & 15;
  int wr = wave >> 1, wc = wave & 1;

  __shared__ short Al[2][64][64];
  __shared__ short Bl[2][128][64];

  const int r8 = lane >> 3;
  const int scol = ((lane & 7) ^ r8) << 3;

  v4f acc[2][4];
#pragma unroll
  for (int m = 0; m < 2; ++m)
#pragma unroll
    for (int n = 0; n < 4; ++n) acc[m][n] = (v4f){0.f, 0.f, 0.f, 0.f};

  auto stage = [&](int kb, int bbuf) {
#pragma unroll
    for (int i = 0; i < 2; ++i) {
      int c = wave * 2 + i;
      gll16(z + (size_t)(bm * 64 + c * 8 + r8) * D_ + kb + scol, &Al[bbuf][c * 8][0]);
    }
#pragma unroll
    for (int i = 0; i < 4; ++i) {
      int c = wave * 4 + i;
      gll16(wt + (size_t)(bn * 128 + c * 8 + r8) * D_ + kb + scol, &Bl[bbuf][c * 8][0]);
    }
  };

  stage(0, 0);
  __syncthreads();

  for (int kt = 0; kt < D_ / 64; ++kt) {
    int bbuf = kt & 1;
    if (kt + 1 < D_ / 64) stage((kt + 1) * 64, bbuf ^ 1);
    v8s af[2][2], bf[4][2];
#pragma unroll
    for (int m = 0; m < 2; ++m) {
      int row = wr * 32 + m * 16 + ll;
#pragma unroll
      for (int c = 0; c < 2; ++c)
        af[m][c] = *(const v8s*)&Al[bbuf][row][(((c << 2) | lh) ^ (ll & 7)) << 3];
    }
#pragma unroll
    for (int n = 0; n < 4; ++n) {
      int row = wc * 64 + n * 16 + ll;
#pragma unroll
      for (int c = 0; c < 2; ++c)
        bf[n][c] = *(const v8s*)&Bl[bbuf][row][(((c << 2) | lh) ^ (ll & 7)) << 3];
    }
#pragma unroll
    for (int m = 0; m < 2; ++m)
#pragma unroll
      for (int n = 0; n < 4; ++n)
#pragma unroll
        for (int c = 0; c < 2; ++c)
          acc[m][n] = __builtin_amdgcn_mfma_f32_16x16x32_bf16(af[m][c], bf[n][c], acc[m][n], 0, 0, 0);
    __syncthreads();
  }

#pragma unroll
  for (int m = 0; m < 2; ++m) {
    int gr = bm * 64 + wr * 32 + m * 16 + lh * 4;
#pragma unroll
    for (int n = 0; n < 4; ++n) {
      int gc = bn * 128 + wc * 64 + n * 16 + ll;
      float bo = bias[gc];
#pragma unroll
      for (int r = 0; r < 4; ++r)
        out[(size_t)(gr + r) * D_ + gc] = acc[m][n][r] + bo;
    }
  }
}

extern "C" void kernel_launch(void* const* d_in, const int* in_sizes, int n_in,
                              void* d_out, int out_size, void* d_ws, size_t ws_size,
                              hipStream_t stream) {
  const float* residual = (const float*)d_in[0];
  const float* q = (const float*)d_in[1];
  const float* k = (const float*)d_in[2];
  const float* v = (const float*)d_in[3];
  const float* W = (const float*)d_in[4];
  const float* bO = (const float*)d_in[5];
  float* out = (float*)d_out;

  const size_t half = (size_t)B_ * S_ * D_;
  short* z = (short*)d_ws;
  short* kbf = z + half;
  short* vtb = kbf + half;
  short* wtb = vtb + half;

  hipMemcpyAsync(out, residual, half * sizeof(float), hipMemcpyDeviceToDevice, stream);

  cvt_bf16_kernel<<<half / 2048, 256, 0, stream>>>(k, kbf);
  cvt_vt_kernel<<<B_ * H_ * (S_ / 64), 256, 0, stream>>>(v, vtb);
  cvt_wt_kernel<<<(D_ / 64) * (D_ / 64), 256, 0, stream>>>(W, wtb);

  attn_kernel<<<256, 256, 0, stream>>>(q, kbf, vtb, z);
  proj_kernel<<<dim3((B_ * S_) / 64, D_ / 128), 256, 0, stream>>>(z, wtb, bO, out + half);
}

// Round 4
// 94.131 us; speedup vs baseline: 2.8933x; 1.4046x over previous
//
#include <hip/hip_runtime.h>

#define B_ 2
#define S_ 2048
#define D_ 1024
#define H_ 16
#define DH_ 64

typedef short v8s __attribute__((ext_vector_type(8)));
typedef float v4f __attribute__((ext_vector_type(4)));
typedef float v16f __attribute__((ext_vector_type(16)));
typedef unsigned int v2u __attribute__((ext_vector_type(2)));
typedef unsigned int v4u __attribute__((ext_vector_type(4)));

__device__ inline short f2bf(float f) {
  unsigned u = __float_as_uint(f);
  u = (u + 0x7FFFu + ((u >> 16) & 1u)) >> 16;
  return (short)u;
}

__device__ inline unsigned pk_bf16(float lo, float hi) {
  unsigned r;
  asm("v_cvt_pk_bf16_f32 %0, %1, %2" : "=v"(r) : "v"(lo), "v"(hi));
  return r;
}

__device__ inline void gll16(const void* g, void* l) {
  __builtin_amdgcn_global_load_lds(
      (const __attribute__((address_space(1))) void*)g,
      (__attribute__((address_space(3))) void*)l, 16, 0, 0);
}

// ---------------- pre-convert kernels ----------------
__global__ __launch_bounds__(256) void cvt_bf16_kernel(const float* __restrict__ in,
                                                       short* __restrict__ out) {
  int i = blockIdx.x * blockDim.x + threadIdx.x;
  float4 a = ((const float4*)in)[2 * i];
  float4 b = ((const float4*)in)[2 * i + 1];
  v8s t;
  t[0] = f2bf(a.x); t[1] = f2bf(a.y); t[2] = f2bf(a.z); t[3] = f2bf(a.w);
  t[4] = f2bf(b.x); t[5] = f2bf(b.y); t[6] = f2bf(b.z); t[7] = f2bf(b.w);
  ((v8s*)out)[i] = t;
}

// v [b][s][h*64+d] f32 -> vt [(b*H+h)*64+d][s] bf16
__global__ __launch_bounds__(256) void cvt_vt_kernel(const float* __restrict__ v,
                                                     short* __restrict__ vt) {
  int bid = blockIdx.x;
  int st = bid & 31;
  int bh = bid >> 5;
  int b = bh >> 4, h = bh & 15;
  int tid = threadIdx.x;
  __shared__ short t[64][64 + 8];
  int r = tid >> 2, c16 = (tid & 3) * 16;
  const float* vp = v + ((size_t)(b * S_ + st * 64 + r)) * D_ + h * DH_ + c16;
  for (int i = 0; i < 16; i += 4) {
    float4 a = *(const float4*)(vp + i);
    t[r][c16 + i + 0] = f2bf(a.x);
    t[r][c16 + i + 1] = f2bf(a.y);
    t[r][c16 + i + 2] = f2bf(a.z);
    t[r][c16 + i + 3] = f2bf(a.w);
  }
  __syncthreads();
  short* op = vt + ((size_t)((b * H_ + h) * DH_ + r)) * S_ + st * 64 + c16;
  v8s o0, o1;
  for (int j = 0; j < 8; ++j) { o0[j] = t[c16 + j][r]; o1[j] = t[c16 + 8 + j][r]; }
  *(v8s*)op = o0;
  *(v8s*)(op + 8) = o1;
}

// W [k][m] f32 -> wt [m][k] bf16
__global__ __launch_bounds__(256) void cvt_wt_kernel(const float* __restrict__ w,
                                                     short* __restrict__ wt) {
  int bid = blockIdx.x;
  int tk = bid & 15, tm = bid >> 4;
  int tid = threadIdx.x;
  __shared__ short t[64][64 + 8];
  int r = tid >> 2, c16 = (tid & 3) * 16;
  const float* wp = w + (size_t)(tk * 64 + r) * D_ + tm * 64 + c16;
  for (int i = 0; i < 16; i += 4) {
    float4 a = *(const float4*)(wp + i);
    t[r][c16 + i + 0] = f2bf(a.x);
    t[r][c16 + i + 1] = f2bf(a.y);
    t[r][c16 + i + 2] = f2bf(a.z);
    t[r][c16 + i + 3] = f2bf(a.w);
  }
  __syncthreads();
  short* op = wt + (size_t)(tm * 64 + r) * D_ + tk * 64 + c16;
  v8s o0, o1;
  for (int j = 0; j < 8; ++j) { o0[j] = t[c16 + j][r]; o1[j] = t[c16 + 8 + j][r]; }
  *(v8s*)op = o0;
  *(v8s*)(op + 8) = o1;
}

// ---------------- fused causal flash attention -> z (bf16) ----------------
// 1024 blocks of 128 threads (2 waves x 32 q-rows). Block = (bh = bid&31,
// q-tile qt). qt = t<16 ? t : 47-t so in-order round-robin gives each CU
// exactly 66 K-tile-units; bh = bid&31 pins each head to one XCD (L2 reuse).
// 32x32x16 MFMA, swapped QK^T, in-register softmax, permlane P exchange.
__global__ __launch_bounds__(128, 2) void attn_kernel(
    const float* __restrict__ q, const short* __restrict__ kbf,
    const short* __restrict__ vtb, short* __restrict__ z) {
  int bid = blockIdx.x;
  int bh = bid & 31;
  int b = bh >> 4, h = bh & 15;
  int t = bid >> 5;
  int qt = t < 16 ? t : 47 - t;

  int tid = threadIdx.x;
  int wave = tid >> 6, lane = tid & 63;
  int l31 = lane & 31, h32 = lane >> 5;

  __shared__ short Klds[2][64][64];  // [key][d] swizzled
  __shared__ short Vlds[2][64][64];  // [d][key] swizzled
  __shared__ short Olds[2][32][64];  // per-wave epilogue transpose

  const int qbase = qt * 64;
  const int qrow0 = qbase + wave * 32;
  const int ntiles = qt + 1;

  const int lr8 = lane >> 3;
  const int scol = ((lane & 7) ^ lr8) << 3;  // pre-swizzled source col (shorts)

  const short* pk_ = kbf + (size_t)b * S_ * D_ + h * DH_ +
                     (size_t)(wave * 8 + lr8) * D_ + scol;
  const short* pv_ = vtb + (size_t)(b * H_ + h) * DH_ * S_ +
                     (size_t)(wave * 8 + lr8) * S_ + scol;

  // Q fragments (pre-scaled by 1/8): lane holds Q^T[d = d4*16+h32*8+j][q=l31]
  v8s qf[4];
  {
    const float* qp = q + (size_t)(b * S_ + qrow0 + l31) * D_ + h * DH_ + h32 * 8;
#pragma unroll
    for (int d4 = 0; d4 < 4; ++d4) {
      float4 x = *(const float4*)(qp + d4 * 16);
      float4 y = *(const float4*)(qp + d4 * 16 + 4);
      v8s tq;
      tq[0] = f2bf(x.x * 0.125f); tq[1] = f2bf(x.y * 0.125f);
      tq[2] = f2bf(x.z * 0.125f); tq[3] = f2bf(x.w * 0.125f);
      tq[4] = f2bf(y.x * 0.125f); tq[5] = f2bf(y.y * 0.125f);
      tq[6] = f2bf(y.z * 0.125f); tq[7] = f2bf(y.w * 0.125f);
      qf[d4] = tq;
    }
  }

  v16f O0, O1;
#pragma unroll
  for (int r = 0; r < 16; ++r) { O0[r] = 0.f; O1[r] = 0.f; }
  float M = -INFINITY, L = 0.f;

  const int swz = (l31 & 7) << 3;

  auto stage = [&](int buf) {
#pragma unroll
    for (int i = 0; i < 4; ++i)
      gll16(pk_ + (size_t)i * 16 * D_, &Klds[buf][i * 16 + wave * 8][0]);
#pragma unroll
    for (int i = 0; i < 4; ++i)
      gll16(pv_ + (size_t)i * 16 * S_, &Vlds[buf][i * 16 + wave * 8][0]);
    pk_ += 64 * D_;
    pv_ += 64;
  };

  stage(0);
  __syncthreads();

  for (int s = 0; s < ntiles; ++s) {
    int cur = s & 1;
    int kb = s * 64;
    if (s + 1 < ntiles) stage(cur ^ 1);

    bool skip1 = (kb >= qrow0);       // keys kb+32.. all > every q of wave
    bool msk = (kb + 63 > qrow0);

    // QK^T swapped: S^T[k][q], k rows per lane = (r&3)+8*(r>>2)+4*h32 (+32)
    __builtin_amdgcn_s_setprio(1);
    v16f S0, S1;
#pragma unroll
    for (int r = 0; r < 16; ++r) { S0[r] = 0.f; S1[r] = 0.f; }
#pragma unroll
    for (int d4 = 0; d4 < 4; ++d4) {
      v8s kf = *(const v8s*)&Klds[cur][l31][(((d4 << 1) | h32) << 3) ^ swz];
      S0 = __builtin_amdgcn_mfma_f32_32x32x16_bf16(kf, qf[d4], S0, 0, 0, 0);
    }
    if (!skip1) {
#pragma unroll
      for (int d4 = 0; d4 < 4; ++d4) {
        v8s kf = *(const v8s*)&Klds[cur][32 + l31][(((d4 << 1) | h32) << 3) ^ swz];
        S1 = __builtin_amdgcn_mfma_f32_32x32x16_bf16(kf, qf[d4], S1, 0, 0, 0);
      }
    }
    __builtin_amdgcn_s_setprio(0);

    int qg = qrow0 + l31;
    float pmax = -3.0e38f;
    if (msk) {
#pragma unroll
      for (int r = 0; r < 16; ++r) {
        int kl = kb + (r & 3) + 8 * (r >> 2) + 4 * h32;
        if (kl > qg) S0[r] = -1e30f;
        pmax = fmaxf(pmax, S0[r]);
      }
      if (!skip1) {
#pragma unroll
        for (int r = 0; r < 16; ++r) {
          int kl = kb + 32 + (r & 3) + 8 * (r >> 2) + 4 * h32;
          if (kl > qg) S1[r] = -1e30f;
          pmax = fmaxf(pmax, S1[r]);
        }
      }
    } else {
#pragma unroll
      for (int r = 0; r < 16; ++r) pmax = fmaxf(pmax, fmaxf(S0[r], S1[r]));
    }
    pmax = fmaxf(pmax, __shfl_xor(pmax, 32));

    bool defer = __all(pmax <= M + 8.f) != 0;   // T13 defer-max
    if (!defer) {
      float Mn = fmaxf(M, pmax);
      float al = __expf(M - Mn);
#pragma unroll
      for (int r = 0; r < 16; ++r) { O0[r] *= al; O1[r] *= al; }
      L *= al;
      M = Mn;
    }

    float rs = 0.f;
    unsigned pw0[8], pw1[8];
#pragma unroll
    for (int r = 0; r < 16; ++r) { S0[r] = __expf(S0[r] - M); rs += S0[r]; }
#pragma unroll
    for (int w = 0; w < 8; ++w) pw0[w] = pk_bf16(S0[2 * w], S0[2 * w + 1]);
    if (!skip1) {
#pragma unroll
      for (int r = 0; r < 16; ++r) { S1[r] = __expf(S1[r] - M); rs += S1[r]; }
#pragma unroll
      for (int w = 0; w < 8; ++w) pw1[w] = pk_bf16(S1[2 * w], S1[2 * w + 1]);
    }
    rs += __shfl_xor(rs, 32);
    L += rs;

    // PV: O^T[d][q] += V^T[d][k] P^T[k][q]; B-frag built via permlane32_swap
    __builtin_amdgcn_s_setprio(1);
#pragma unroll
    for (int ks = 0; ks < 2; ++ks) {
      v2u a = __builtin_amdgcn_permlane32_swap(pw0[ks * 4 + 0], pw0[ks * 4 + 2], false, false);
      v2u c = __builtin_amdgcn_permlane32_swap(pw0[ks * 4 + 1], pw0[ks * 4 + 3], false, false);
      v4u fw; fw.x = a.x; fw.y = c.x; fw.z = a.y; fw.w = c.y;
      v8s pb = __builtin_bit_cast(v8s, fw);
      v8s vf0 = *(const v8s*)&Vlds[cur][l31][(((ks << 1) | h32) << 3) ^ swz];
      O0 = __builtin_amdgcn_mfma_f32_32x32x16_bf16(vf0, pb, O0, 0, 0, 0);
      v8s vf1 = *(const v8s*)&Vlds[cur][32 + l31][(((ks << 1) | h32) << 3) ^ swz];
      O1 = __builtin_amdgcn_mfma_f32_32x32x16_bf16(vf1, pb, O1, 0, 0, 0);
    }
    if (!skip1) {
#pragma unroll
      for (int ks = 0; ks < 2; ++ks) {
        v2u a = __builtin_amdgcn_permlane32_swap(pw1[ks * 4 + 0], pw1[ks * 4 + 2], false, false);
        v2u c = __builtin_amdgcn_permlane32_swap(pw1[ks * 4 + 1], pw1[ks * 4 + 3], false, false);
        v4u fw; fw.x = a.x; fw.y = c.x; fw.z = a.y; fw.w = c.y;
        v8s pb = __builtin_bit_cast(v8s, fw);
        v8s vf0 = *(const v8s*)&Vlds[cur][l31][((((ks + 2) << 1) | h32) << 3) ^ swz];
        O0 = __builtin_amdgcn_mfma_f32_32x32x16_bf16(vf0, pb, O0, 0, 0, 0);
        v8s vf1 = *(const v8s*)&Vlds[cur][32 + l31][((((ks + 2) << 1) | h32) << 3) ^ swz];
        O1 = __builtin_amdgcn_mfma_f32_32x32x16_bf16(vf1, pb, O1, 0, 0, 0);
      }
    }
    __builtin_amdgcn_s_setprio(0);
    __syncthreads();
  }

  // Epilogue: O^T regs -> Olds (bf16, swizzled transpose) -> coalesced z
  float inv = 1.f / L;
#pragma unroll
  for (int w = 0; w < 8; ++w) {
    int d0 = 8 * (w >> 1) + 2 * (w & 1) + 4 * h32;
    unsigned u0 = pk_bf16(O0[2 * w] * inv, O0[2 * w + 1] * inv);
    *(unsigned*)&Olds[wave][l31][d0 ^ swz] = u0;
    unsigned u1 = pk_bf16(O1[2 * w] * inv, O1[2 * w + 1] * inv);
    *(unsigned*)&Olds[wave][l31][(32 + d0) ^ swz] = u1;
  }
  asm volatile("s_waitcnt lgkmcnt(0)" ::: "memory");
  int qr = lane >> 1, hf = lane & 1;
  int swr = (qr & 7) << 3;
  short* zp = z + (size_t)(b * S_ + qrow0 + qr) * D_ + h * DH_ + hf * 32;
#pragma unroll
  for (int j = 0; j < 4; ++j) {
    v8s tv = *(const v8s*)&Olds[wave][qr][((hf * 32 + j * 8) ^ swr)];
    *(v8s*)(zp + j * 8) = tv;
  }
}

// ---------------- projection GEMM: out = z @ Wt^T + b ----------------
__global__ __launch_bounds__(256) void proj_kernel(
    const short* __restrict__ z, const short* __restrict__ wt,
    const float* __restrict__ bias, float* __restrict__ out) {
  int bm = blockIdx.x, bn = blockIdx.y;
  int tid = threadIdx.x;
  int wave = tid >> 6, lane = tid & 63, lh = lane >> 4, ll = lane & 15;
  int wr = wave >> 1, wc = wave & 1;

  __shared__ short Al[2][64][64];
  __shared__ short Bl[2][128][64];

  const int r8 = lane >> 3;
  const int scol = ((lane & 7) ^ r8) << 3;

  v4f acc[2][4];
#pragma unroll
  for (int m = 0; m < 2; ++m)
#pragma unroll
    for (int n = 0; n < 4; ++n) acc[m][n] = (v4f){0.f, 0.f, 0.f, 0.f};

  auto stage = [&](int kb, int bbuf) {
#pragma unroll
    for (int i = 0; i < 2; ++i) {
      int c = wave * 2 + i;
      gll16(z + (size_t)(bm * 64 + c * 8 + r8) * D_ + kb + scol, &Al[bbuf][c * 8][0]);
    }
#pragma unroll
    for (int i = 0; i < 4; ++i) {
      int c = wave * 4 + i;
      gll16(wt + (size_t)(bn * 128 + c * 8 + r8) * D_ + kb + scol, &Bl[bbuf][c * 8][0]);
    }
  };

  stage(0, 0);
  __syncthreads();

  for (int kt = 0; kt < D_ / 64; ++kt) {
    int bbuf = kt & 1;
    if (kt + 1 < D_ / 64) stage((kt + 1) * 64, bbuf ^ 1);
    v8s af[2][2], bf[4][2];
#pragma unroll
    for (int m = 0; m < 2; ++m) {
      int row = wr * 32 + m * 16 + ll;
#pragma unroll
      for (int c = 0; c < 2; ++c)
        af[m][c] = *(const v8s*)&Al[bbuf][row][(((c << 2) | lh) ^ (ll & 7)) << 3];
    }
#pragma unroll
    for (int n = 0; n < 4; ++n) {
      int row = wc * 64 + n * 16 + ll;
#pragma unroll
      for (int c = 0; c < 2; ++c)
        bf[n][c] = *(const v8s*)&Bl[bbuf][row][(((c << 2) | lh) ^ (ll & 7)) << 3];
    }
#pragma unroll
    for (int m = 0; m < 2; ++m)
#pragma unroll
      for (int n = 0; n < 4; ++n)
#pragma unroll
        for (int c = 0; c < 2; ++c)
          acc[m][n] = __builtin_amdgcn_mfma_f32_16x16x32_bf16(af[m][c], bf[n][c], acc[m][n], 0, 0, 0);
    __syncthreads();
  }

#pragma unroll
  for (int m = 0; m < 2; ++m) {
    int gr = bm * 64 + wr * 32 + m * 16 + lh * 4;
#pragma unroll
    for (int n = 0; n < 4; ++n) {
      int gc = bn * 128 + wc * 64 + n * 16 + ll;
      float bo = bias[gc];
#pragma unroll
      for (int r = 0; r < 4; ++r)
        out[(size_t)(gr + r) * D_ + gc] = acc[m][n][r] + bo;
    }
  }
}

extern "C" void kernel_launch(void* const* d_in, const int* in_sizes, int n_in,
                              void* d_out, int out_size, void* d_ws, size_t ws_size,
                              hipStream_t stream) {
  const float* residual = (const float*)d_in[0];
  const float* q = (const float*)d_in[1];
  const float* k = (const float*)d_in[2];
  const float* v = (const float*)d_in[3];
  const float* W = (const float*)d_in[4];
  const float* bO = (const float*)d_in[5];
  float* out = (float*)d_out;

  const size_t half = (size_t)B_ * S_ * D_;
  short* z = (short*)d_ws;
  short* kbf = z + half;
  short* vtb = kbf + half;
  short* wtb = vtb + half;

  hipMemcpyAsync(out, residual, half * sizeof(float), hipMemcpyDeviceToDevice, stream);

  cvt_bf16_kernel<<<half / 2048, 256, 0, stream>>>(k, kbf);
  cvt_vt_kernel<<<B_ * H_ * (S_ / 64), 256, 0, stream>>>(v, vtb);
  cvt_wt_kernel<<<(D_ / 64) * (D_ / 64), 256, 0, stream>>>(W, wtb);

  attn_kernel<<<1024, 128, 0, stream>>>(q, kbf, vtb, z);
  proj_kernel<<<dim3((B_ * S_) / 64, D_ / 128), 256, 0, stream>>>(z, wtb, bO, out + half);
}

// Round 5
// 88.933 us; speedup vs baseline: 3.0624x; 1.0585x over previous
//
#include <hip/hip_runtime.h>

#define B_ 2
#define S_ 2048
#define D_ 1024
#define H_ 16
#define DH_ 64
#define NP_ 2048  // partial tiles: 32 bh * 64 qt32

typedef short v8s __attribute__((ext_vector_type(8)));
typedef float v4f __attribute__((ext_vector_type(4)));
typedef float v16f __attribute__((ext_vector_type(16)));
typedef unsigned int v2u __attribute__((ext_vector_type(2)));
typedef unsigned int v4u __attribute__((ext_vector_type(4)));
typedef unsigned int uint32;

__device__ inline short f2bf(float f) {
  unsigned u = __float_as_uint(f);
  u = (u + 0x7FFFu + ((u >> 16) & 1u)) >> 16;
  return (short)u;
}

__device__ inline unsigned pk_bf16(float lo, float hi) {
  unsigned r;
  asm("v_cvt_pk_bf16_f32 %0, %1, %2" : "=v"(r) : "v"(lo), "v"(hi));
  return r;
}

__device__ inline void gll16(const void* g, void* l) {
  __builtin_amdgcn_global_load_lds(
      (const __attribute__((address_space(1))) void*)g,
      (__attribute__((address_space(3))) void*)l, 16, 0, 0);
}

// ---------------- pre-convert kernels ----------------
__global__ __launch_bounds__(256) void cvt_bf16_kernel(const float* __restrict__ in,
                                                       short* __restrict__ out) {
  int i = blockIdx.x * blockDim.x + threadIdx.x;
  float4 a = ((const float4*)in)[2 * i];
  float4 b = ((const float4*)in)[2 * i + 1];
  v8s t;
  t[0] = f2bf(a.x); t[1] = f2bf(a.y); t[2] = f2bf(a.z); t[3] = f2bf(a.w);
  t[4] = f2bf(b.x); t[5] = f2bf(b.y); t[6] = f2bf(b.z); t[7] = f2bf(b.w);
  ((v8s*)out)[i] = t;
}

// v [b][s][h*64+d] f32 -> vt [(b*H+h)*64+d][s] bf16
__global__ __launch_bounds__(256) void cvt_vt_kernel(const float* __restrict__ v,
                                                     short* __restrict__ vt) {
  int bid = blockIdx.x;
  int st = bid & 31;
  int bh = bid >> 5;
  int b = bh >> 4, h = bh & 15;
  int tid = threadIdx.x;
  __shared__ short t[64][64 + 8];
  int r = tid >> 2, c16 = (tid & 3) * 16;
  const float* vp = v + ((size_t)(b * S_ + st * 64 + r)) * D_ + h * DH_ + c16;
  for (int i = 0; i < 16; i += 4) {
    float4 a = *(const float4*)(vp + i);
    t[r][c16 + i + 0] = f2bf(a.x);
    t[r][c16 + i + 1] = f2bf(a.y);
    t[r][c16 + i + 2] = f2bf(a.z);
    t[r][c16 + i + 3] = f2bf(a.w);
  }
  __syncthreads();
  short* op = vt + ((size_t)((b * H_ + h) * DH_ + r)) * S_ + st * 64 + c16;
  v8s o0, o1;
  for (int j = 0; j < 8; ++j) { o0[j] = t[c16 + j][r]; o1[j] = t[c16 + 8 + j][r]; }
  *(v8s*)op = o0;
  *(v8s*)(op + 8) = o1;
}

// W [k][m] f32 -> wt [m][k] bf16
__global__ __launch_bounds__(256) void cvt_wt_kernel(const float* __restrict__ w,
                                                     short* __restrict__ wt) {
  int bid = blockIdx.x;
  int tk = bid & 15, tm = bid >> 4;
  int tid = threadIdx.x;
  __shared__ short t[64][64 + 8];
  int r = tid >> 2, c16 = (tid & 3) * 16;
  const float* wp = w + (size_t)(tk * 64 + r) * D_ + tm * 64 + c16;
  for (int i = 0; i < 16; i += 4) {
    float4 a = *(const float4*)(wp + i);
    t[r][c16 + i + 0] = f2bf(a.x);
    t[r][c16 + i + 1] = f2bf(a.y);
    t[r][c16 + i + 2] = f2bf(a.z);
    t[r][c16 + i + 3] = f2bf(a.w);
  }
  __syncthreads();
  short* op = wt + (size_t)(tm * 64 + r) * D_ + tk * 64 + c16;
  v8s o0, o1;
  for (int j = 0; j < 8; ++j) { o0[j] = t[c16 + j][r]; o1[j] = t[c16 + 8 + j][r]; }
  *(v8s*)op = o0;
  *(v8s*)(op + 8) = o1;
}

// ---------------- split-K flash attention -> unnormalized partials ----------
// grid = 32qt * SPLITS * 32bh blocks of 128 thr (2 waves x 32 q-rows).
// qt mapped big-first; each split handles half the K-tile range.
// Counted-vmcnt pipeline: raw s_barrier + s_waitcnt vmcnt(8), dbuf LDS.
// Partials: Opart u32 [sp][p][dpair 0..31][q 0..31] (bf16 pairs, native MFMA
// layout, unnormalized), ML float2 [sp][p][q 0..31] = {M, L}.
template <int SPLITS>
__global__ __launch_bounds__(128, 2) void attn_kernel(
    const float* __restrict__ q, const short* __restrict__ kbf,
    const short* __restrict__ vtb, uint32* __restrict__ Opart,
    float2* __restrict__ ML) {
  constexpr int SHIFT = (SPLITS == 2 ? 6 : 5);
  int bid = blockIdx.x;
  int bh = bid & 31;
  int sp = (SPLITS == 2) ? ((bid >> 5) & 1) : 0;
  int qt = 31 - (bid >> SHIFT);  // big blocks first
  int b = bh >> 4, h = bh & 15;

  int nt = qt + 1;
  int hs = (nt + 1) >> 1;
  int t0 = (SPLITS == 2 && sp == 1) ? hs : 0;
  int t1 = (SPLITS == 2 && sp == 0) ? hs - 1 : qt;  // inclusive

  int tid = threadIdx.x;
  int wave = tid >> 6, lane = tid & 63;
  int l31 = lane & 31, h32 = lane >> 5;

  __shared__ short Klds[2][64][64];  // [key][d] swizzled
  __shared__ short Vlds[2][64][64];  // [d][key] swizzled

  const int qrow0 = qt * 64 + wave * 32;
  const int lr8 = lane >> 3;
  const int scol = ((lane & 7) ^ lr8) << 3;

  const short* kbase = kbf + (size_t)b * S_ * D_ + h * DH_;
  const short* vbase = vtb + (size_t)(b * H_ + h) * DH_ * S_;

  // Q fragments (pre-scaled by 1/8): lane holds Q^T[d][q=l31]
  v8s qf[4];
  {
    const float* qp = q + (size_t)(b * S_ + qrow0 + l31) * D_ + h * DH_ + h32 * 8;
#pragma unroll
    for (int d4 = 0; d4 < 4; ++d4) {
      float4 x = *(const float4*)(qp + d4 * 16);
      float4 y = *(const float4*)(qp + d4 * 16 + 4);
      v8s tq;
      tq[0] = f2bf(x.x * 0.125f); tq[1] = f2bf(x.y * 0.125f);
      tq[2] = f2bf(x.z * 0.125f); tq[3] = f2bf(x.w * 0.125f);
      tq[4] = f2bf(y.x * 0.125f); tq[5] = f2bf(y.y * 0.125f);
      tq[6] = f2bf(y.z * 0.125f); tq[7] = f2bf(y.w * 0.125f);
      qf[d4] = tq;
    }
  }

  v16f O0, O1;
#pragma unroll
  for (int r = 0; r < 16; ++r) { O0[r] = 0.f; O1[r] = 0.f; }
  float M = -INFINITY, L = 0.f;
  const int swz = (l31 & 7) << 3;

  auto stage = [&](int t, int buf) {
    const short* kp = kbase + (size_t)(t * 64 + wave * 8 + lr8) * D_ + scol;
    const short* vp = vbase + (size_t)(wave * 8 + lr8) * S_ + t * 64 + scol;
#pragma unroll
    for (int i = 0; i < 4; ++i)
      gll16(kp + (size_t)(i * 16) * D_, &Klds[buf][i * 16 + wave * 8][0]);
#pragma unroll
    for (int i = 0; i < 4; ++i)
      gll16(vp + (size_t)(i * 16) * S_, &Vlds[buf][i * 16 + wave * 8][0]);
  };

  if (t0 <= t1) {
    stage(t0, t0 & 1);
    stage(min(t0 + 1, t1), (t0 + 1) & 1);
  }

  for (int s = t0; s <= t1; ++s) {
    int cur = s & 1;
    int kb = s * 64;
    asm volatile("s_waitcnt vmcnt(8)" ::: "memory");
    __builtin_amdgcn_sched_barrier(0);
    __builtin_amdgcn_s_barrier();
    __builtin_amdgcn_sched_barrier(0);

    bool skip1 = (kb >= qrow0);
    bool msk = (kb + 63 > qrow0);

    __builtin_amdgcn_s_setprio(1);
    v16f S0, S1;
#pragma unroll
    for (int r = 0; r < 16; ++r) { S0[r] = 0.f; S1[r] = 0.f; }
#pragma unroll
    for (int d4 = 0; d4 < 4; ++d4) {
      v8s kf = *(const v8s*)&Klds[cur][l31][(((d4 << 1) | h32) << 3) ^ swz];
      S0 = __builtin_amdgcn_mfma_f32_32x32x16_bf16(kf, qf[d4], S0, 0, 0, 0);
    }
    if (!skip1) {
#pragma unroll
      for (int d4 = 0; d4 < 4; ++d4) {
        v8s kf = *(const v8s*)&Klds[cur][32 + l31][(((d4 << 1) | h32) << 3) ^ swz];
        S1 = __builtin_amdgcn_mfma_f32_32x32x16_bf16(kf, qf[d4], S1, 0, 0, 0);
      }
    }
    __builtin_amdgcn_s_setprio(0);

    int qg = qrow0 + l31;
    float pmax = -3.0e38f;
    if (msk) {
#pragma unroll
      for (int r = 0; r < 16; ++r) {
        int kl = kb + (r & 3) + 8 * (r >> 2) + 4 * h32;
        if (kl > qg) S0[r] = -1e30f;
        pmax = fmaxf(pmax, S0[r]);
      }
      if (!skip1) {
#pragma unroll
        for (int r = 0; r < 16; ++r) {
          int kl = kb + 32 + (r & 3) + 8 * (r >> 2) + 4 * h32;
          if (kl > qg) S1[r] = -1e30f;
          pmax = fmaxf(pmax, S1[r]);
        }
      }
    } else {
#pragma unroll
      for (int r = 0; r < 16; ++r) pmax = fmaxf(pmax, fmaxf(S0[r], S1[r]));
    }
    pmax = fmaxf(pmax, __shfl_xor(pmax, 32));

    bool defer = __all(pmax <= M + 8.f) != 0;  // T13 defer-max
    if (!defer) {
      float Mn = fmaxf(M, pmax);
      float al = __expf(M - Mn);
#pragma unroll
      for (int r = 0; r < 16; ++r) { O0[r] *= al; O1[r] *= al; }
      L *= al;
      M = Mn;
    }

    float rs = 0.f;
    unsigned pw0[8], pw1[8];
#pragma unroll
    for (int r = 0; r < 16; ++r) { S0[r] = __expf(S0[r] - M); rs += S0[r]; }
#pragma unroll
    for (int w = 0; w < 8; ++w) pw0[w] = pk_bf16(S0[2 * w], S0[2 * w + 1]);
    if (!skip1) {
#pragma unroll
      for (int r = 0; r < 16; ++r) { S1[r] = __expf(S1[r] - M); rs += S1[r]; }
#pragma unroll
      for (int w = 0; w < 8; ++w) pw1[w] = pk_bf16(S1[2 * w], S1[2 * w + 1]);
    }
    rs += __shfl_xor(rs, 32);
    L += rs;

    __builtin_amdgcn_s_setprio(1);
#pragma unroll
    for (int ks = 0; ks < 2; ++ks) {
      v2u a = __builtin_amdgcn_permlane32_swap(pw0[ks * 4 + 0], pw0[ks * 4 + 2], false, false);
      v2u c = __builtin_amdgcn_permlane32_swap(pw0[ks * 4 + 1], pw0[ks * 4 + 3], false, false);
      v4u fw; fw.x = a.x; fw.y = c.x; fw.z = a.y; fw.w = c.y;
      v8s pb = __builtin_bit_cast(v8s, fw);
      v8s vf0 = *(const v8s*)&Vlds[cur][l31][(((ks << 1) | h32) << 3) ^ swz];
      O0 = __builtin_amdgcn_mfma_f32_32x32x16_bf16(vf0, pb, O0, 0, 0, 0);
      v8s vf1 = *(const v8s*)&Vlds[cur][32 + l31][(((ks << 1) | h32) << 3) ^ swz];
      O1 = __builtin_amdgcn_mfma_f32_32x32x16_bf16(vf1, pb, O1, 0, 0, 0);
    }
    if (!skip1) {
#pragma unroll
      for (int ks = 0; ks < 2; ++ks) {
        v2u a = __builtin_amdgcn_permlane32_swap(pw1[ks * 4 + 0], pw1[ks * 4 + 2], false, false);
        v2u c = __builtin_amdgcn_permlane32_swap(pw1[ks * 4 + 1], pw1[ks * 4 + 3], false, false);
        v4u fw; fw.x = a.x; fw.y = c.x; fw.z = a.y; fw.w = c.y;
        v8s pb = __builtin_bit_cast(v8s, fw);
        v8s vf0 = *(const v8s*)&Vlds[cur][l31][((((ks + 2) << 1) | h32) << 3) ^ swz];
        O0 = __builtin_amdgcn_mfma_f32_32x32x16_bf16(vf0, pb, O0, 0, 0, 0);
        v8s vf1 = *(const v8s*)&Vlds[cur][32 + l31][((((ks + 2) << 1) | h32) << 3) ^ swz];
        O1 = __builtin_amdgcn_mfma_f32_32x32x16_bf16(vf1, pb, O1, 0, 0, 0);
      }
    }
    __builtin_amdgcn_s_setprio(0);

    __builtin_amdgcn_s_barrier();  // all reads of buf[cur] done before rewrite
    __builtin_amdgcn_sched_barrier(0);
    stage(min(s + 2, t1), cur);
  }

  // Epilogue: unnormalized partial write (native layout, coalesced in q)
  int p = bh * 64 + qt * 2 + wave;
  uint32* Op = Opart + ((size_t)(sp * NP_ + p)) * 1024;
#pragma unroll
  for (int w = 0; w < 8; ++w) {
    int dpair = 4 * (w >> 1) + (w & 1) + 2 * h32;
    Op[dpair * 32 + l31] = pk_bf16(O0[2 * w], O0[2 * w + 1]);
    Op[(16 + dpair) * 32 + l31] = pk_bf16(O1[2 * w], O1[2 * w + 1]);
  }
  if (h32 == 0) {
    float2 ml; ml.x = M; ml.y = L;
    ML[(size_t)(sp * NP_ + p) * 32 + l31] = ml;
  }
}

// ---------------- merge partials -> z (bf16) ----------------
template <int SPLITS>
__global__ __launch_bounds__(128) void merge_kernel(
    const uint32* __restrict__ Opart, const float2* __restrict__ ML,
    short* __restrict__ z) {
  int p = blockIdx.x;
  int tid = threadIdx.x;
  int q = tid & 31, g = tid >> 5;

  float2 ml0 = ML[(size_t)p * 32 + q];
  float f0, f1 = 0.f;
  if constexpr (SPLITS == 2) {
    float2 ml1 = ML[(size_t)(NP_ + p) * 32 + q];
    float Mx = fmaxf(ml0.x, ml1.x);
    float s0 = __expf(ml0.x - Mx), s1 = __expf(ml1.x - Mx);
    float invL = 1.f / (ml0.y * s0 + ml1.y * s1);
    f0 = s0 * invL; f1 = s1 * invL;
  } else {
    f0 = 1.f / ml0.y;
  }

  __shared__ uint32 T[32][33];
  const uint32* O0 = Opart + (size_t)p * 1024;
  const uint32* O1 = Opart + (size_t)(NP_ + p) * 1024;
#pragma unroll
  for (int j = 0; j < 8; ++j) {
    int dp = g * 8 + j;
    uint32 u0 = O0[dp * 32 + q];
    float lo = __uint_as_float(u0 << 16) * f0;
    float hi = __uint_as_float(u0 & 0xFFFF0000u) * f0;
    if constexpr (SPLITS == 2) {
      uint32 u1 = O1[dp * 32 + q];
      lo += __uint_as_float(u1 << 16) * f1;
      hi += __uint_as_float(u1 & 0xFFFF0000u) * f1;
    }
    T[q][dp] = pk_bf16(lo, hi);
  }
  __syncthreads();
  int q2 = tid >> 2, c = (tid & 3) * 8;
  int srow = (p & 63) * 32 + q2;
  int b = p >> 10, h = (p >> 6) & 15;
  uint32* zp = (uint32*)z + ((size_t)(b * S_ + srow)) * (D_ / 2) + h * 32 + c;
#pragma unroll
  for (int j = 0; j < 8; ++j) zp[j] = T[q2][c + j];
}

// ---------------- projection GEMM: out = z @ Wt^T + b ----------------
__global__ __launch_bounds__(256) void proj_kernel(
    const short* __restrict__ z, const short* __restrict__ wt,
    const float* __restrict__ bias, float* __restrict__ out) {
  int bm = blockIdx.x, bn = blockIdx.y;
  int tid = threadIdx.x;
  int wave = tid >> 6, lane = tid & 63, lh = lane >> 4, ll = lane & 15;
  int wr = wave >> 1, wc = wave & 1;

  __shared__ short Al[2][64][64];
  __shared__ short Bl[2][128][64];

  const int r8 = lane >> 3;
  const int scol = ((lane & 7) ^ r8) << 3;

  v4f acc[2][4];
#pragma unroll
  for (int m = 0; m < 2; ++m)
#pragma unroll
    for (int n = 0; n < 4; ++n) acc[m][n] = (v4f){0.f, 0.f, 0.f, 0.f};

  auto stage = [&](int kb, int bbuf) {
#pragma unroll
    for (int i = 0; i < 2; ++i) {
      int c = wave * 2 + i;
      gll16(z + (size_t)(bm * 64 + c * 8 + r8) * D_ + kb + scol, &Al[bbuf][c * 8][0]);
    }
#pragma unroll
    for (int i = 0; i < 4; ++i) {
      int c = wave * 4 + i;
      gll16(wt + (size_t)(bn * 128 + c * 8 + r8) * D_ + kb + scol, &Bl[bbuf][c * 8][0]);
    }
  };

  stage(0, 0);
  __syncthreads();

  for (int kt = 0; kt < D_ / 64; ++kt) {
    int bbuf = kt & 1;
    if (kt + 1 < D_ / 64) stage((kt + 1) * 64, bbuf ^ 1);
    v8s af[2][2], bf[4][2];
#pragma unroll
    for (int m = 0; m < 2; ++m) {
      int row = wr * 32 + m * 16 + ll;
#pragma unroll
      for (int c = 0; c < 2; ++c)
        af[m][c] = *(const v8s*)&Al[bbuf][row][(((c << 2) | lh) ^ (ll & 7)) << 3];
    }
#pragma unroll
    for (int n = 0; n < 4; ++n) {
      int row = wc * 64 + n * 16 + ll;
#pragma unroll
      for (int c = 0; c < 2; ++c)
        bf[n][c] = *(const v8s*)&Bl[bbuf][row][(((c << 2) | lh) ^ (ll & 7)) << 3];
    }
#pragma unroll
    for (int m = 0; m < 2; ++m)
#pragma unroll
      for (int n = 0; n < 4; ++n)
#pragma unroll
        for (int c = 0; c < 2; ++c)
          acc[m][n] = __builtin_amdgcn_mfma_f32_16x16x32_bf16(af[m][c], bf[n][c], acc[m][n], 0, 0, 0);
    __syncthreads();
  }

#pragma unroll
  for (int m = 0; m < 2; ++m) {
    int gr = bm * 64 + wr * 32 + m * 16 + lh * 4;
#pragma unroll
    for (int n = 0; n < 4; ++n) {
      int gc = bn * 128 + wc * 64 + n * 16 + ll;
      float bo = bias[gc];
#pragma unroll
      for (int r = 0; r < 4; ++r)
        out[(size_t)(gr + r) * D_ + gc] = acc[m][n][r] + bo;
    }
  }
}

extern "C" void kernel_launch(void* const* d_in, const int* in_sizes, int n_in,
                              void* d_out, int out_size, void* d_ws, size_t ws_size,
                              hipStream_t stream) {
  const float* residual = (const float*)d_in[0];
  const float* q = (const float*)d_in[1];
  const float* k = (const float*)d_in[2];
  const float* v = (const float*)d_in[3];
  const float* W = (const float*)d_in[4];
  const float* bO = (const float*)d_in[5];
  float* out = (float*)d_out;

  const size_t half = (size_t)B_ * S_ * D_;
  char* ws = (char*)d_ws;
  short* z = (short*)ws;                        // 8 MB
  short* kbf = z + half;                        // 8 MB
  short* vtb = kbf + half;                      // 8 MB
  short* wtb = vtb + half;                      // 2 MB
  char* pbase = (char*)(wtb + (size_t)D_ * D_);
  const size_t opart_b = (size_t)NP_ * 1024 * 4;  // per split: 8 MB
  const size_t ml_b = (size_t)NP_ * 32 * 8;       // per split: 0.5 MB
  const size_t base_b = (size_t)pbase - (size_t)ws;

  hipMemcpyAsync(out, residual, half * sizeof(float), hipMemcpyDeviceToDevice, stream);

  cvt_bf16_kernel<<<half / 2048, 256, 0, stream>>>(k, kbf);
  cvt_vt_kernel<<<B_ * H_ * (S_ / 64), 256, 0, stream>>>(v, vtb);
  cvt_wt_kernel<<<(D_ / 64) * (D_ / 64), 256, 0, stream>>>(W, wtb);

  if (ws_size >= base_b + 2 * (opart_b + ml_b)) {
    uint32* Opart = (uint32*)pbase;
    float2* ML = (float2*)(pbase + 2 * opart_b);
    attn_kernel<2><<<2048, 128, 0, stream>>>(q, kbf, vtb, Opart, ML);
    merge_kernel<2><<<NP_, 128, 0, stream>>>(Opart, ML, z);
  } else {
    uint32* Opart = (uint32*)pbase;
    float2* ML = (float2*)(pbase + opart_b);
    attn_kernel<1><<<1024, 128, 0, stream>>>(q, kbf, vtb, Opart, ML);
    merge_kernel<1><<<NP_, 128, 0, stream>>>(Opart, ML, z);
  }

  proj_kernel<<<dim3((B_ * S_) / 64, D_ / 128), 256, 0, stream>>>(z, wtb, bO, out + half);
}

// Round 6
// 77.092 us; speedup vs baseline: 3.5328x; 1.1536x over previous
//
#include <hip/hip_runtime.h>

#define B_ 2
#define S_ 2048
#define D_ 1024
#define H_ 16
#define DH_ 64
#define NP_ 2048  // partial tiles: 32 bh * 64 qt32

typedef short v8s __attribute__((ext_vector_type(8)));
typedef float v4f __attribute__((ext_vector_type(4)));
typedef float v16f __attribute__((ext_vector_type(16)));
typedef unsigned int v2u __attribute__((ext_vector_type(2)));
typedef unsigned int v4u __attribute__((ext_vector_type(4)));
typedef unsigned int uint32;

__device__ inline short f2bf(float f) {
  unsigned u = __float_as_uint(f);
  u = (u + 0x7FFFu + ((u >> 16) & 1u)) >> 16;
  return (short)u;
}

__device__ inline unsigned pk_bf16(float lo, float hi) {
  unsigned r;
  asm("v_cvt_pk_bf16_f32 %0, %1, %2" : "=v"(r) : "v"(lo), "v"(hi));
  return r;
}

__device__ inline void gll16(const void* g, void* l) {
  __builtin_amdgcn_global_load_lds(
      (const __attribute__((address_space(1))) void*)g,
      (__attribute__((address_space(3))) void*)l, 16, 0, 0);
}

// ---------------- pre-convert kernels ----------------
__global__ __launch_bounds__(256) void cvt_bf16_kernel(const float* __restrict__ in,
                                                       short* __restrict__ out) {
  int i = blockIdx.x * blockDim.x + threadIdx.x;
  float4 a = ((const float4*)in)[2 * i];
  float4 b = ((const float4*)in)[2 * i + 1];
  v8s t;
  t[0] = f2bf(a.x); t[1] = f2bf(a.y); t[2] = f2bf(a.z); t[3] = f2bf(a.w);
  t[4] = f2bf(b.x); t[5] = f2bf(b.y); t[6] = f2bf(b.z); t[7] = f2bf(b.w);
  ((v8s*)out)[i] = t;
}

// v [b][s][h*64+d] f32 -> vt [(b*H+h)*64+d][s] bf16
__global__ __launch_bounds__(256) void cvt_vt_kernel(const float* __restrict__ v,
                                                     short* __restrict__ vt) {
  int bid = blockIdx.x;
  int st = bid & 31;
  int bh = bid >> 5;
  int b = bh >> 4, h = bh & 15;
  int tid = threadIdx.x;
  __shared__ short t[64][64 + 8];
  int r = tid >> 2, c16 = (tid & 3) * 16;
  const float* vp = v + ((size_t)(b * S_ + st * 64 + r)) * D_ + h * DH_ + c16;
  for (int i = 0; i < 16; i += 4) {
    float4 a = *(const float4*)(vp + i);
    t[r][c16 + i + 0] = f2bf(a.x);
    t[r][c16 + i + 1] = f2bf(a.y);
    t[r][c16 + i + 2] = f2bf(a.z);
    t[r][c16 + i + 3] = f2bf(a.w);
  }
  __syncthreads();
  short* op = vt + ((size_t)((b * H_ + h) * DH_ + r)) * S_ + st * 64 + c16;
  v8s o0, o1;
  for (int j = 0; j < 8; ++j) { o0[j] = t[c16 + j][r]; o1[j] = t[c16 + 8 + j][r]; }
  *(v8s*)op = o0;
  *(v8s*)(op + 8) = o1;
}

// W [k][m] f32 -> wt [m][k] bf16
__global__ __launch_bounds__(256) void cvt_wt_kernel(const float* __restrict__ w,
                                                     short* __restrict__ wt) {
  int bid = blockIdx.x;
  int tk = bid & 15, tm = bid >> 4;
  int tid = threadIdx.x;
  __shared__ short t[64][64 + 8];
  int r = tid >> 2, c16 = (tid & 3) * 16;
  const float* wp = w + (size_t)(tk * 64 + r) * D_ + tm * 64 + c16;
  for (int i = 0; i < 16; i += 4) {
    float4 a = *(const float4*)(wp + i);
    t[r][c16 + i + 0] = f2bf(a.x);
    t[r][c16 + i + 1] = f2bf(a.y);
    t[r][c16 + i + 2] = f2bf(a.z);
    t[r][c16 + i + 3] = f2bf(a.w);
  }
  __syncthreads();
  short* op = wt + (size_t)(tm * 64 + r) * D_ + tk * 64 + c16;
  v8s o0, o1;
  for (int j = 0; j < 8; ++j) { o0[j] = t[c16 + j][r]; o1[j] = t[c16 + 8 + j][r]; }
  *(v8s*)op = o0;
  *(v8s*)(op + 8) = o1;
}

// ---------------- split-K flash attention -> unnormalized partials ----------
// grid = 32qt * SPLITS * 32bh blocks of 128 thr (2 waves x 32 q-rows), qt
// big-first; SPLITS=2 halves the K-range per block. 16KB LDS single-buffer ->
// 8 blocks/CU = whole grid resident; cross-block TLP hides staging latency.
// No-max softmax in log2 domain: Q pre-scaled by 0.125*log2e, P = exp2(S'),
// masked -> -1e30 -> 0. Constant shift cancels in O/L; scores bounded ~|6|
// so f32 exp can't overflow. Partials: Opart u32 [sp][p][dpair][q] (bf16
// pairs, unnormalized, native MFMA layout); Lsum float [sp][p][q].
template <int SPLITS>
__global__ __launch_bounds__(128, 4) void attn_kernel(
    const float* __restrict__ q, const short* __restrict__ kbf,
    const short* __restrict__ vtb, uint32* __restrict__ Opart,
    float* __restrict__ Lsum) {
  constexpr int SHIFT = (SPLITS == 2 ? 6 : 5);
  int bid = blockIdx.x;
  int bh = bid & 31;
  int sp = (SPLITS == 2) ? ((bid >> 5) & 1) : 0;
  int qt = 31 - (int)(bid >> SHIFT);  // big blocks first
  int b = bh >> 4, h = bh & 15;

  int nt = qt + 1;
  int hs = (nt + 1) >> 1;
  int t0 = (SPLITS == 2 && sp == 1) ? hs : 0;
  int t1 = (SPLITS == 2 && sp == 0) ? hs - 1 : qt;  // inclusive

  int tid = threadIdx.x;
  int wave = tid >> 6, lane = tid & 63;
  int l31 = lane & 31, h32 = lane >> 5;

  __shared__ short Klds[64][64];  // [key][d] swizzled
  __shared__ short Vlds[64][64];  // [d][key] swizzled

  const int qrow0 = qt * 64 + wave * 32;
  const int lr8 = lane >> 3;
  const int scol = ((lane & 7) ^ lr8) << 3;

  const short* pk_ = kbf + (size_t)b * S_ * D_ + h * DH_ +
                     (size_t)(t0 * 64 + wave * 8 + lr8) * D_ + scol;
  const short* pv_ = vtb + (size_t)(b * H_ + h) * DH_ * S_ +
                     (size_t)(wave * 8 + lr8) * S_ + t0 * 64 + scol;

  // Q fragments pre-scaled by 0.125*log2e: lane holds Q^T[d][q=l31]
  v8s qf[4];
  {
    const float* qp = q + (size_t)(b * S_ + qrow0 + l31) * D_ + h * DH_ + h32 * 8;
    const float sc = 0.125f * 1.44269504f;
#pragma unroll
    for (int d4 = 0; d4 < 4; ++d4) {
      float4 x = *(const float4*)(qp + d4 * 16);
      float4 y = *(const float4*)(qp + d4 * 16 + 4);
      v8s tq;
      tq[0] = f2bf(x.x * sc); tq[1] = f2bf(x.y * sc);
      tq[2] = f2bf(x.z * sc); tq[3] = f2bf(x.w * sc);
      tq[4] = f2bf(y.x * sc); tq[5] = f2bf(y.y * sc);
      tq[6] = f2bf(y.z * sc); tq[7] = f2bf(y.w * sc);
      qf[d4] = tq;
    }
  }

  v16f O0, O1;
#pragma unroll
  for (int r = 0; r < 16; ++r) { O0[r] = 0.f; O1[r] = 0.f; }
  float L = 0.f;
  const int swz = (l31 & 7) << 3;

  for (int s = t0; s <= t1; ++s) {
    // stage K/V tile (single buffer)
#pragma unroll
    for (int i = 0; i < 4; ++i)
      gll16(pk_ + (size_t)(i * 16) * D_, &Klds[i * 16 + wave * 8][0]);
#pragma unroll
    for (int i = 0; i < 4; ++i)
      gll16(pv_ + (size_t)(i * 16) * S_, &Vlds[i * 16 + wave * 8][0]);
    pk_ += (size_t)64 * D_;
    pv_ += 64;
    asm volatile("s_waitcnt vmcnt(0)" ::: "memory");
    __builtin_amdgcn_sched_barrier(0);
    __builtin_amdgcn_s_barrier();
    __builtin_amdgcn_sched_barrier(0);

    int kb = s * 64;
    bool skip1 = (kb >= qrow0);       // keys kb+32.. all masked for this wave
    bool msk = (kb + 63 > qrow0);

    // QK^T swapped: S^T[k][q], k rows per lane = (r&3)+8*(r>>2)+4*h32 (+32)
    __builtin_amdgcn_s_setprio(1);
    v16f S0, S1;
#pragma unroll
    for (int r = 0; r < 16; ++r) { S0[r] = 0.f; S1[r] = 0.f; }
#pragma unroll
    for (int d4 = 0; d4 < 4; ++d4) {
      v8s kf = *(const v8s*)&Klds[l31][(((d4 << 1) | h32) << 3) ^ swz];
      S0 = __builtin_amdgcn_mfma_f32_32x32x16_bf16(kf, qf[d4], S0, 0, 0, 0);
    }
    if (!skip1) {
#pragma unroll
      for (int d4 = 0; d4 < 4; ++d4) {
        v8s kf = *(const v8s*)&Klds[32 + l31][(((d4 << 1) | h32) << 3) ^ swz];
        S1 = __builtin_amdgcn_mfma_f32_32x32x16_bf16(kf, qf[d4], S1, 0, 0, 0);
      }
    }
    __builtin_amdgcn_s_setprio(0);

    int qg = qrow0 + l31;
    if (msk) {
#pragma unroll
      for (int r = 0; r < 16; ++r) {
        int kl = kb + (r & 3) + 8 * (r >> 2) + 4 * h32;
        if (kl > qg) S0[r] = -1e30f;
      }
      if (!skip1) {
#pragma unroll
        for (int r = 0; r < 16; ++r) {
          int kl = kb + 32 + (r & 3) + 8 * (r >> 2) + 4 * h32;
          if (kl > qg) S1[r] = -1e30f;
        }
      }
    }

    float rs = 0.f;
    unsigned pw0[8], pw1[8];
#pragma unroll
    for (int r = 0; r < 16; ++r) {
      S0[r] = __builtin_amdgcn_exp2f(S0[r]);
      rs += S0[r];
    }
#pragma unroll
    for (int w = 0; w < 8; ++w) pw0[w] = pk_bf16(S0[2 * w], S0[2 * w + 1]);
    if (!skip1) {
#pragma unroll
      for (int r = 0; r < 16; ++r) {
        S1[r] = __builtin_amdgcn_exp2f(S1[r]);
        rs += S1[r];
      }
#pragma unroll
      for (int w = 0; w < 8; ++w) pw1[w] = pk_bf16(S1[2 * w], S1[2 * w + 1]);
    }
    rs += __shfl_xor(rs, 32);
    L += rs;

    // PV: O^T[d][q] += V^T[d][k] P^T[k][q]; B-frag via permlane32_swap
    __builtin_amdgcn_s_setprio(1);
#pragma unroll
    for (int ks = 0; ks < 2; ++ks) {
      v2u a = __builtin_amdgcn_permlane32_swap(pw0[ks * 4 + 0], pw0[ks * 4 + 2], false, false);
      v2u c = __builtin_amdgcn_permlane32_swap(pw0[ks * 4 + 1], pw0[ks * 4 + 3], false, false);
      v4u fw; fw.x = a.x; fw.y = c.x; fw.z = a.y; fw.w = c.y;
      v8s pb = __builtin_bit_cast(v8s, fw);
      v8s vf0 = *(const v8s*)&Vlds[l31][(((ks << 1) | h32) << 3) ^ swz];
      O0 = __builtin_amdgcn_mfma_f32_32x32x16_bf16(vf0, pb, O0, 0, 0, 0);
      v8s vf1 = *(const v8s*)&Vlds[32 + l31][(((ks << 1) | h32) << 3) ^ swz];
      O1 = __builtin_amdgcn_mfma_f32_32x32x16_bf16(vf1, pb, O1, 0, 0, 0);
    }
    if (!skip1) {
#pragma unroll
      for (int ks = 0; ks < 2; ++ks) {
        v2u a = __builtin_amdgcn_permlane32_swap(pw1[ks * 4 + 0], pw1[ks * 4 + 2], false, false);
        v2u c = __builtin_amdgcn_permlane32_swap(pw1[ks * 4 + 1], pw1[ks * 4 + 3], false, false);
        v4u fw; fw.x = a.x; fw.y = c.x; fw.z = a.y; fw.w = c.y;
        v8s pb = __builtin_bit_cast(v8s, fw);
        v8s vf0 = *(const v8s*)&Vlds[l31][((((ks + 2) << 1) | h32) << 3) ^ swz];
        O0 = __builtin_amdgcn_mfma_f32_32x32x16_bf16(vf0, pb, O0, 0, 0, 0);
        v8s vf1 = *(const v8s*)&Vlds[32 + l31][((((ks + 2) << 1) | h32) << 3) ^ swz];
        O1 = __builtin_amdgcn_mfma_f32_32x32x16_bf16(vf1, pb, O1, 0, 0, 0);
      }
    }
    __builtin_amdgcn_s_setprio(0);

    __builtin_amdgcn_sched_barrier(0);
    __builtin_amdgcn_s_barrier();  // all reads done before next stage rewrite
    __builtin_amdgcn_sched_barrier(0);
  }

  // Epilogue: unnormalized partial write (native layout, coalesced in q)
  int p = bh * 64 + qt * 2 + wave;
  uint32* Op = Opart + ((size_t)(sp * NP_ + p)) * 1024;
#pragma unroll
  for (int w = 0; w < 8; ++w) {
    int dpair = 4 * (w >> 1) + (w & 1) + 2 * h32;
    Op[dpair * 32 + l31] = pk_bf16(O0[2 * w], O0[2 * w + 1]);
    Op[(16 + dpair) * 32 + l31] = pk_bf16(O1[2 * w], O1[2 * w + 1]);
  }
  if (h32 == 0) Lsum[(size_t)(sp * NP_ + p) * 32 + l31] = L;
}

// ---------------- merge partials -> z (bf16) ----------------
template <int SPLITS>
__global__ __launch_bounds__(128) void merge_kernel(
    const uint32* __restrict__ Opart, const float* __restrict__ Lsum,
    short* __restrict__ z) {
  int p = blockIdx.x;
  int tid = threadIdx.x;
  int qq = tid & 31, g = tid >> 5;

  float Lt = Lsum[(size_t)p * 32 + qq];
  if constexpr (SPLITS == 2) Lt += Lsum[(size_t)(NP_ + p) * 32 + qq];
  float f = 1.f / Lt;

  __shared__ uint32 T[32][33];
  const uint32* O0 = Opart + (size_t)p * 1024;
  const uint32* O1 = Opart + (size_t)(NP_ + p) * 1024;
#pragma unroll
  for (int j = 0; j < 8; ++j) {
    int dp = g * 8 + j;
    uint32 u0 = O0[dp * 32 + qq];
    float lo = __uint_as_float(u0 << 16);
    float hi = __uint_as_float(u0 & 0xFFFF0000u);
    if constexpr (SPLITS == 2) {
      uint32 u1 = O1[dp * 32 + qq];
      lo += __uint_as_float(u1 << 16);
      hi += __uint_as_float(u1 & 0xFFFF0000u);
    }
    T[qq][dp] = pk_bf16(lo * f, hi * f);
  }
  __syncthreads();
  int q2 = tid >> 2, c = (tid & 3) * 8;
  int srow = (p & 63) * 32 + q2;
  int b = p >> 10, h = (p >> 6) & 15;
  uint32* zp = (uint32*)z + ((size_t)(b * S_ + srow)) * (D_ / 2) + h * 32 + c;
#pragma unroll
  for (int j = 0; j < 8; ++j) zp[j] = T[q2][c + j];
}

// ---------------- projection GEMM: out = z @ Wt^T + b ----------------
__global__ __launch_bounds__(256) void proj_kernel(
    const short* __restrict__ z, const short* __restrict__ wt,
    const float* __restrict__ bias, float* __restrict__ out) {
  int bm = blockIdx.x, bn = blockIdx.y;
  int tid = threadIdx.x;
  int wave = tid >> 6, lane = tid & 63, lh = lane >> 4, ll = lane & 15;
  int wr = wave >> 1, wc = wave & 1;

  __shared__ short Al[2][64][64];
  __shared__ short Bl[2][128][64];

  const int r8 = lane >> 3;
  const int scol = ((lane & 7) ^ r8) << 3;

  v4f acc[2][4];
#pragma unroll
  for (int m = 0; m < 2; ++m)
#pragma unroll
    for (int n = 0; n < 4; ++n) acc[m][n] = (v4f){0.f, 0.f, 0.f, 0.f};

  auto stage = [&](int kb, int bbuf) {
#pragma unroll
    for (int i = 0; i < 2; ++i) {
      int c = wave * 2 + i;
      gll16(z + (size_t)(bm * 64 + c * 8 + r8) * D_ + kb + scol, &Al[bbuf][c * 8][0]);
    }
#pragma unroll
    for (int i = 0; i < 4; ++i) {
      int c = wave * 4 + i;
      gll16(wt + (size_t)(bn * 128 + c * 8 + r8) * D_ + kb + scol, &Bl[bbuf][c * 8][0]);
    }
  };

  stage(0, 0);
  __syncthreads();

  for (int kt = 0; kt < D_ / 64; ++kt) {
    int bbuf = kt & 1;
    if (kt + 1 < D_ / 64) stage((kt + 1) * 64, bbuf ^ 1);
    v8s af[2][2], bf[4][2];
#pragma unroll
    for (int m = 0; m < 2; ++m) {
      int row = wr * 32 + m * 16 + ll;
#pragma unroll
      for (int c = 0; c < 2; ++c)
        af[m][c] = *(const v8s*)&Al[bbuf][row][(((c << 2) | lh) ^ (ll & 7)) << 3];
    }
#pragma unroll
    for (int n = 0; n < 4; ++n) {
      int row = wc * 64 + n * 16 + ll;
#pragma unroll
      for (int c = 0; c < 2; ++c)
        bf[n][c] = *(const v8s*)&Bl[bbuf][row][(((c << 2) | lh) ^ (ll & 7)) << 3];
    }
#pragma unroll
    for (int m = 0; m < 2; ++m)
#pragma unroll
      for (int n = 0; n < 4; ++n)
#pragma unroll
        for (int c = 0; c < 2; ++c)
          acc[m][n] = __builtin_amdgcn_mfma_f32_16x16x32_bf16(af[m][c], bf[n][c], acc[m][n], 0, 0, 0);
    __syncthreads();
  }

#pragma unroll
  for (int m = 0; m < 2; ++m) {
    int gr = bm * 64 + wr * 32 + m * 16 + lh * 4;
#pragma unroll
    for (int n = 0; n < 4; ++n) {
      int gc = bn * 128 + wc * 64 + n * 16 + ll;
      float bo = bias[gc];
#pragma unroll
      for (int r = 0; r < 4; ++r)
        out[(size_t)(gr + r) * D_ + gc] = acc[m][n][r] + bo;
    }
  }
}

extern "C" void kernel_launch(void* const* d_in, const int* in_sizes, int n_in,
                              void* d_out, int out_size, void* d_ws, size_t ws_size,
                              hipStream_t stream) {
  const float* residual = (const float*)d_in[0];
  const float* q = (const float*)d_in[1];
  const float* k = (const float*)d_in[2];
  const float* v = (const float*)d_in[3];
  const float* W = (const float*)d_in[4];
  const float* bO = (const float*)d_in[5];
  float* out = (float*)d_out;

  const size_t half = (size_t)B_ * S_ * D_;
  char* ws = (char*)d_ws;
  short* z = (short*)ws;                        // 8 MB
  short* kbf = z + half;                        // 8 MB
  short* vtb = kbf + half;                      // 8 MB
  short* wtb = vtb + half;                      // 2 MB
  char* pbase = (char*)(wtb + (size_t)D_ * D_);
  const size_t opart_b = (size_t)NP_ * 1024 * 4;  // per split: 8 MB
  const size_t l_b = (size_t)NP_ * 32 * 4;        // per split: 256 KB
  const size_t base_b = (size_t)pbase - (size_t)ws;

  hipMemcpyAsync(out, residual, half * sizeof(float), hipMemcpyDeviceToDevice, stream);

  cvt_bf16_kernel<<<half / 2048, 256, 0, stream>>>(k, kbf);
  cvt_vt_kernel<<<B_ * H_ * (S_ / 64), 256, 0, stream>>>(v, vtb);
  cvt_wt_kernel<<<(D_ / 64) * (D_ / 64), 256, 0, stream>>>(W, wtb);

  if (ws_size >= base_b + 2 * (opart_b + l_b)) {
    uint32* Opart = (uint32*)pbase;
    float* Lsum = (float*)(pbase + 2 * opart_b);
    attn_kernel<2><<<2048, 128, 0, stream>>>(q, kbf, vtb, Opart, Lsum);
    merge_kernel<2><<<NP_, 128, 0, stream>>>(Opart, Lsum, z);
  } else {
    uint32* Opart = (uint32*)pbase;
    float* Lsum = (float*)(pbase + opart_b);
    attn_kernel<1><<<1024, 128, 0, stream>>>(q, kbf, vtb, Opart, Lsum);
    merge_kernel<1><<<NP_, 128, 0, stream>>>(Opart, Lsum, z);
  }

  proj_kernel<<<dim3((B_ * S_) / 64, D_ / 128), 256, 0, stream>>>(z, wtb, bO, out + half);
}

// Round 7
// 75.491 us; speedup vs baseline: 3.6077x; 1.0212x over previous
//
#include <hip/hip_runtime.h>

#define B_ 2
#define S_ 2048
#define D_ 1024
#define H_ 16
#define DH_ 64
#define NP_ 2048  // partial tiles: 32 bh * 64 qt32

typedef short v8s __attribute__((ext_vector_type(8)));
typedef float v4f __attribute__((ext_vector_type(4)));
typedef float v16f __attribute__((ext_vector_type(16)));
typedef unsigned int v2u __attribute__((ext_vector_type(2)));
typedef unsigned int v4u __attribute__((ext_vector_type(4)));
typedef unsigned int uint32;

__device__ inline short f2bf(float f) {
  unsigned u = __float_as_uint(f);
  u = (u + 0x7FFFu + ((u >> 16) & 1u)) >> 16;
  return (short)u;
}

__device__ inline unsigned pk_bf16(float lo, float hi) {
  unsigned r;
  asm("v_cvt_pk_bf16_f32 %0, %1, %2" : "=v"(r) : "v"(lo), "v"(hi));
  return r;
}

__device__ inline void gll16(const void* g, void* l) {
  __builtin_amdgcn_global_load_lds(
      (const __attribute__((address_space(1))) void*)g,
      (__attribute__((address_space(3))) void*)l, 16, 0, 0);
}

// ---------------- pre-convert kernels ----------------
__global__ __launch_bounds__(256) void cvt_bf16_kernel(const float* __restrict__ in,
                                                       short* __restrict__ out) {
  int i = blockIdx.x * blockDim.x + threadIdx.x;
  float4 a = ((const float4*)in)[2 * i];
  float4 b = ((const float4*)in)[2 * i + 1];
  v8s t;
  t[0] = f2bf(a.x); t[1] = f2bf(a.y); t[2] = f2bf(a.z); t[3] = f2bf(a.w);
  t[4] = f2bf(b.x); t[5] = f2bf(b.y); t[6] = f2bf(b.z); t[7] = f2bf(b.w);
  ((v8s*)out)[i] = t;
}

// v [b][s][h*64+d] f32 -> vt [(b*H+h)*64+d][s] bf16
__global__ __launch_bounds__(256) void cvt_vt_kernel(const float* __restrict__ v,
                                                     short* __restrict__ vt) {
  int bid = blockIdx.x;
  int st = bid & 31;
  int bh = bid >> 5;
  int b = bh >> 4, h = bh & 15;
  int tid = threadIdx.x;
  __shared__ short t[64][64 + 8];
  int r = tid >> 2, c16 = (tid & 3) * 16;
  const float* vp = v + ((size_t)(b * S_ + st * 64 + r)) * D_ + h * DH_ + c16;
  for (int i = 0; i < 16; i += 4) {
    float4 a = *(const float4*)(vp + i);
    t[r][c16 + i + 0] = f2bf(a.x);
    t[r][c16 + i + 1] = f2bf(a.y);
    t[r][c16 + i + 2] = f2bf(a.z);
    t[r][c16 + i + 3] = f2bf(a.w);
  }
  __syncthreads();
  short* op = vt + ((size_t)((b * H_ + h) * DH_ + r)) * S_ + st * 64 + c16;
  v8s o0, o1;
  for (int j = 0; j < 8; ++j) { o0[j] = t[c16 + j][r]; o1[j] = t[c16 + 8 + j][r]; }
  *(v8s*)op = o0;
  *(v8s*)(op + 8) = o1;
}

// W [k][m] f32 -> wt [m][k] bf16
__global__ __launch_bounds__(256) void cvt_wt_kernel(const float* __restrict__ w,
                                                     short* __restrict__ wt) {
  int bid = blockIdx.x;
  int tk = bid & 15, tm = bid >> 4;
  int tid = threadIdx.x;
  __shared__ short t[64][64 + 8];
  int r = tid >> 2, c16 = (tid & 3) * 16;
  const float* wp = w + (size_t)(tk * 64 + r) * D_ + tm * 64 + c16;
  for (int i = 0; i < 16; i += 4) {
    float4 a = *(const float4*)(wp + i);
    t[r][c16 + i + 0] = f2bf(a.x);
    t[r][c16 + i + 1] = f2bf(a.y);
    t[r][c16 + i + 2] = f2bf(a.z);
    t[r][c16 + i + 3] = f2bf(a.w);
  }
  __syncthreads();
  short* op = wt + (size_t)(tm * 64 + r) * D_ + tk * 64 + c16;
  v8s o0, o1;
  for (int j = 0; j < 8; ++j) { o0[j] = t[c16 + j][r]; o1[j] = t[c16 + 8 + j][r]; }
  *(v8s*)op = o0;
  *(v8s*)(op + 8) = o1;
}

// ---------------- split-K flash attention -> unnormalized partials ----------
// Same structure as R6 (passed). Additionally each block copies its slice of
// the residual pass-through (fold the serial memcpy under attn's compute).
template <int SPLITS>
__global__ __launch_bounds__(128, 4) void attn_kernel(
    const float* __restrict__ q, const short* __restrict__ kbf,
    const short* __restrict__ vtb, uint32* __restrict__ Opart,
    float* __restrict__ Lsum, const float* __restrict__ residual,
    float* __restrict__ res_out) {
  constexpr int SHIFT = (SPLITS == 2 ? 6 : 5);
  int bid = blockIdx.x;
  int bh = bid & 31;
  int sp = (SPLITS == 2) ? ((bid >> 5) & 1) : 0;
  int qt = 31 - (int)(bid >> SHIFT);  // big blocks first
  int b = bh >> 4, h = bh & 15;

  int nt = qt + 1;
  int hs = (nt + 1) >> 1;
  int t0 = (SPLITS == 2 && sp == 1) ? hs : 0;
  int t1 = (SPLITS == 2 && sp == 0) ? hs - 1 : qt;  // inclusive

  int tid = threadIdx.x;
  int wave = tid >> 6, lane = tid & 63;
  int l31 = lane & 31, h32 = lane >> 5;

  __shared__ short Klds[64][64];  // [key][d] swizzled
  __shared__ short Vlds[64][64];  // [d][key] swizzled

  const int qrow0 = qt * 64 + wave * 32;
  const int lr8 = lane >> 3;
  const int scol = ((lane & 7) ^ lr8) << 3;

  const short* pk_ = kbf + (size_t)b * S_ * D_ + h * DH_ +
                     (size_t)(t0 * 64 + wave * 8 + lr8) * D_ + scol;
  const short* pv_ = vtb + (size_t)(b * H_ + h) * DH_ * S_ +
                     (size_t)(wave * 8 + lr8) * S_ + t0 * 64 + scol;

  // Q fragments pre-scaled by 0.125*log2e: lane holds Q^T[d][q=l31]
  v8s qf[4];
  {
    const float* qp = q + (size_t)(b * S_ + qrow0 + l31) * D_ + h * DH_ + h32 * 8;
    const float sc = 0.125f * 1.44269504f;
#pragma unroll
    for (int d4 = 0; d4 < 4; ++d4) {
      float4 x = *(const float4*)(qp + d4 * 16);
      float4 y = *(const float4*)(qp + d4 * 16 + 4);
      v8s tq;
      tq[0] = f2bf(x.x * sc); tq[1] = f2bf(x.y * sc);
      tq[2] = f2bf(x.z * sc); tq[3] = f2bf(x.w * sc);
      tq[4] = f2bf(y.x * sc); tq[5] = f2bf(y.y * sc);
      tq[6] = f2bf(y.z * sc); tq[7] = f2bf(y.w * sc);
      qf[d4] = tq;
    }
  }

  v16f O0, O1;
#pragma unroll
  for (int r = 0; r < 16; ++r) { O0[r] = 0.f; O1[r] = 0.f; }
  float L = 0.f;
  const int swz = (l31 & 7) << 3;

  for (int s = t0; s <= t1; ++s) {
    // stage K/V tile (single buffer)
#pragma unroll
    for (int i = 0; i < 4; ++i)
      gll16(pk_ + (size_t)(i * 16) * D_, &Klds[i * 16 + wave * 8][0]);
#pragma unroll
    for (int i = 0; i < 4; ++i)
      gll16(pv_ + (size_t)(i * 16) * S_, &Vlds[i * 16 + wave * 8][0]);
    pk_ += (size_t)64 * D_;
    pv_ += 64;
    asm volatile("s_waitcnt vmcnt(0)" ::: "memory");
    __builtin_amdgcn_sched_barrier(0);
    __builtin_amdgcn_s_barrier();
    __builtin_amdgcn_sched_barrier(0);

    int kb = s * 64;
    bool skip1 = (kb >= qrow0);       // keys kb+32.. all masked for this wave
    bool msk = (kb + 63 > qrow0);

    // QK^T swapped: S^T[k][q], k rows per lane = (r&3)+8*(r>>2)+4*h32 (+32)
    __builtin_amdgcn_s_setprio(1);
    v16f S0, S1;
#pragma unroll
    for (int r = 0; r < 16; ++r) { S0[r] = 0.f; S1[r] = 0.f; }
#pragma unroll
    for (int d4 = 0; d4 < 4; ++d4) {
      v8s kf = *(const v8s*)&Klds[l31][(((d4 << 1) | h32) << 3) ^ swz];
      S0 = __builtin_amdgcn_mfma_f32_32x32x16_bf16(kf, qf[d4], S0, 0, 0, 0);
    }
    if (!skip1) {
#pragma unroll
      for (int d4 = 0; d4 < 4; ++d4) {
        v8s kf = *(const v8s*)&Klds[32 + l31][(((d4 << 1) | h32) << 3) ^ swz];
        S1 = __builtin_amdgcn_mfma_f32_32x32x16_bf16(kf, qf[d4], S1, 0, 0, 0);
      }
    }
    __builtin_amdgcn_s_setprio(0);

    int qg = qrow0 + l31;
    if (msk) {
#pragma unroll
      for (int r = 0; r < 16; ++r) {
        int kl = kb + (r & 3) + 8 * (r >> 2) + 4 * h32;
        if (kl > qg) S0[r] = -1e30f;
      }
      if (!skip1) {
#pragma unroll
        for (int r = 0; r < 16; ++r) {
          int kl = kb + 32 + (r & 3) + 8 * (r >> 2) + 4 * h32;
          if (kl > qg) S1[r] = -1e30f;
        }
      }
    }

    float rs = 0.f;
    unsigned pw0[8], pw1[8];
#pragma unroll
    for (int r = 0; r < 16; ++r) {
      S0[r] = __builtin_amdgcn_exp2f(S0[r]);
      rs += S0[r];
    }
#pragma unroll
    for (int w = 0; w < 8; ++w) pw0[w] = pk_bf16(S0[2 * w], S0[2 * w + 1]);
    if (!skip1) {
#pragma unroll
      for (int r = 0; r < 16; ++r) {
        S1[r] = __builtin_amdgcn_exp2f(S1[r]);
        rs += S1[r];
      }
#pragma unroll
      for (int w = 0; w < 8; ++w) pw1[w] = pk_bf16(S1[2 * w], S1[2 * w + 1]);
    }
    rs += __shfl_xor(rs, 32);
    L += rs;

    // PV: O^T[d][q] += V^T[d][k] P^T[k][q]; B-frag via permlane32_swap
    __builtin_amdgcn_s_setprio(1);
#pragma unroll
    for (int ks = 0; ks < 2; ++ks) {
      v2u a = __builtin_amdgcn_permlane32_swap(pw0[ks * 4 + 0], pw0[ks * 4 + 2], false, false);
      v2u c = __builtin_amdgcn_permlane32_swap(pw0[ks * 4 + 1], pw0[ks * 4 + 3], false, false);
      v4u fw; fw.x = a.x; fw.y = c.x; fw.z = a.y; fw.w = c.y;
      v8s pb = __builtin_bit_cast(v8s, fw);
      v8s vf0 = *(const v8s*)&Vlds[l31][(((ks << 1) | h32) << 3) ^ swz];
      O0 = __builtin_amdgcn_mfma_f32_32x32x16_bf16(vf0, pb, O0, 0, 0, 0);
      v8s vf1 = *(const v8s*)&Vlds[32 + l31][(((ks << 1) | h32) << 3) ^ swz];
      O1 = __builtin_amdgcn_mfma_f32_32x32x16_bf16(vf1, pb, O1, 0, 0, 0);
    }
    if (!skip1) {
#pragma unroll
      for (int ks = 0; ks < 2; ++ks) {
        v2u a = __builtin_amdgcn_permlane32_swap(pw1[ks * 4 + 0], pw1[ks * 4 + 2], false, false);
        v2u c = __builtin_amdgcn_permlane32_swap(pw1[ks * 4 + 1], pw1[ks * 4 + 3], false, false);
        v4u fw; fw.x = a.x; fw.y = c.x; fw.z = a.y; fw.w = c.y;
        v8s pb = __builtin_bit_cast(v8s, fw);
        v8s vf0 = *(const v8s*)&Vlds[l31][((((ks + 2) << 1) | h32) << 3) ^ swz];
        O0 = __builtin_amdgcn_mfma_f32_32x32x16_bf16(vf0, pb, O0, 0, 0, 0);
        v8s vf1 = *(const v8s*)&Vlds[32 + l31][((((ks + 2) << 1) | h32) << 3) ^ swz];
        O1 = __builtin_amdgcn_mfma_f32_32x32x16_bf16(vf1, pb, O1, 0, 0, 0);
      }
    }
    __builtin_amdgcn_s_setprio(0);

    __builtin_amdgcn_sched_barrier(0);
    __builtin_amdgcn_s_barrier();  // all reads done before next stage rewrite
    __builtin_amdgcn_sched_barrier(0);
  }

  // Epilogue: unnormalized partial write (native layout, coalesced in q)
  int p = bh * 64 + qt * 2 + wave;
  uint32* Op = Opart + ((size_t)(sp * NP_ + p)) * 1024;
#pragma unroll
  for (int w = 0; w < 8; ++w) {
    int dpair = 4 * (w >> 1) + (w & 1) + 2 * h32;
    Op[dpair * 32 + l31] = pk_bf16(O0[2 * w], O0[2 * w + 1]);
    Op[(16 + dpair) * 32 + l31] = pk_bf16(O1[2 * w], O1[2 * w + 1]);
  }
  if (h32 == 0) Lsum[(size_t)(sp * NP_ + p) * 32 + l31] = L;

  // Folded residual pass-through: out[0:B*S*D] = residual
  {
    constexpr int F4 = (SPLITS == 2) ? 4 : 8;
    const float4* rs_ = (const float4*)residual;
    float4* rd_ = (float4*)res_out;
    size_t base = (size_t)bid * (128 * F4) + tid;
#pragma unroll
    for (int j = 0; j < F4; ++j) rd_[base + j * 128] = rs_[base + j * 128];
  }
}

// ---------------- fused merge+projection: out = (O/L) @ Wt^T + b -----------
// BK=64 == DH, so each K-step is exactly one head: A-tile is read from Opart
// (both splits summed in f32, normalized by per-head 1/L) and ds_written into
// the same swizzled Al layout the gll16 path produced. T14 split: loads issue
// before compute, normalize+write after.
template <int SPLITS>
__global__ __launch_bounds__(256) void proj_kernel(
    const uint32* __restrict__ Opart, const float* __restrict__ Lsum,
    const short* __restrict__ wt, const float* __restrict__ bias,
    float* __restrict__ out) {
  int bm = blockIdx.x, bn = blockIdx.y;
  int tid = threadIdx.x;
  int wave = tid >> 6, lane = tid & 63, lh = lane >> 4, ll = lane & 15;
  int wr = wave >> 1, wc = wave & 1;

  __shared__ short Al[2][64][64];
  __shared__ short Bl[2][128][64];

  const int r8 = lane >> 3;
  const int scol = ((lane & 7) ^ r8) << 3;

  // A-staging roles: 2048 u32/tile / 256 thr = 8 each
  const int sq = tid & 31;         // token q within wave-half
  const int sph = tid >> 7;        // attn wave-half -> p offset
  const int sdg = (tid >> 5) & 3;  // dpair group (8 dpairs each)
  const int srow = sph * 32 + sq;  // A/LDS row 0..63
  const int sx7 = srow & 7;

  const int b = bm >> 5, qt = bm & 31;
  const size_t prow = (size_t)(b * 16) * 64 + qt * 2 + sph;  // + kt*64

  v4f acc[2][4];
#pragma unroll
  for (int m = 0; m < 2; ++m)
#pragma unroll
    for (int n = 0; n < 4; ++n) acc[m][n] = (v4f){0.f, 0.f, 0.f, 0.f};

  uint32 a0[8], a1[8];
  float f;

  auto loadA = [&](int kt) {
    size_t p = prow + (size_t)kt * 64;
    const uint32* src = Opart + p * 1024 + (sdg * 8) * 32 + sq;
#pragma unroll
    for (int j = 0; j < 8; ++j) a0[j] = src[j * 32];
    if constexpr (SPLITS == 2) {
      const uint32* src1 = src + (size_t)NP_ * 1024;
#pragma unroll
      for (int j = 0; j < 8; ++j) a1[j] = src1[j * 32];
    }
    float Lt = Lsum[p * 32 + sq];
    if constexpr (SPLITS == 2) Lt += Lsum[((size_t)NP_ + p) * 32 + sq];
    f = 1.f / Lt;
  };

  auto writeA = [&](int buf) {
#pragma unroll
    for (int j = 0; j < 8; ++j) {
      int dp = sdg * 8 + j;
      float lo = __uint_as_float(a0[j] << 16);
      float hi = __uint_as_float(a0[j] & 0xFFFF0000u);
      if constexpr (SPLITS == 2) {
        lo += __uint_as_float(a1[j] << 16);
        hi += __uint_as_float(a1[j] & 0xFFFF0000u);
      }
      uint32 w = pk_bf16(lo * f, hi * f);
      int g = dp >> 2;
      *(uint32*)&Al[buf][srow][(((g ^ sx7) << 3) + ((dp & 3) << 1))] = w;
    }
  };

  auto stageB = [&](int kb, int buf) {
#pragma unroll
    for (int i = 0; i < 4; ++i) {
      int c = wave * 4 + i;
      gll16(wt + (size_t)(bn * 128 + c * 8 + r8) * D_ + kb + scol, &Bl[buf][c * 8][0]);
    }
  };

  loadA(0);
  stageB(0, 0);
  writeA(0);
  __syncthreads();

  for (int kt = 0; kt < 16; ++kt) {
    int buf = kt & 1;
    if (kt + 1 < 16) {
      loadA(kt + 1);
      stageB((kt + 1) * 64, buf ^ 1);
    }
    v8s af[2][2], bf[4][2];
#pragma unroll
    for (int m = 0; m < 2; ++m) {
      int row = wr * 32 + m * 16 + ll;
#pragma unroll
      for (int c = 0; c < 2; ++c)
        af[m][c] = *(const v8s*)&Al[buf][row][(((c << 2) | lh) ^ (ll & 7)) << 3];
    }
#pragma unroll
    for (int n = 0; n < 4; ++n) {
      int row = wc * 64 + n * 16 + ll;
#pragma unroll
      for (int c = 0; c < 2; ++c)
        bf[n][c] = *(const v8s*)&Bl[buf][row][(((c << 2) | lh) ^ (ll & 7)) << 3];
    }
#pragma unroll
    for (int m = 0; m < 2; ++m)
#pragma unroll
      for (int n = 0; n < 4; ++n)
#pragma unroll
        for (int c = 0; c < 2; ++c)
          acc[m][n] = __builtin_amdgcn_mfma_f32_16x16x32_bf16(af[m][c], bf[n][c], acc[m][n], 0, 0, 0);
    if (kt + 1 < 16) writeA(buf ^ 1);
    __syncthreads();
  }

#pragma unroll
  for (int m = 0; m < 2; ++m) {
    int gr = bm * 64 + wr * 32 + m * 16 + lh * 4;
#pragma unroll
    for (int n = 0; n < 4; ++n) {
      int gc = bn * 128 + wc * 64 + n * 16 + ll;
      float bo = bias[gc];
#pragma unroll
      for (int r = 0; r < 4; ++r)
        out[(size_t)(gr + r) * D_ + gc] = acc[m][n][r] + bo;
    }
  }
}

extern "C" void kernel_launch(void* const* d_in, const int* in_sizes, int n_in,
                              void* d_out, int out_size, void* d_ws, size_t ws_size,
                              hipStream_t stream) {
  const float* residual = (const float*)d_in[0];
  const float* q = (const float*)d_in[1];
  const float* k = (const float*)d_in[2];
  const float* v = (const float*)d_in[3];
  const float* W = (const float*)d_in[4];
  const float* bO = (const float*)d_in[5];
  float* out = (float*)d_out;

  const size_t half = (size_t)B_ * S_ * D_;
  char* ws = (char*)d_ws;
  short* kbf = (short*)ws;                      // 8.4 MB
  short* vtb = kbf + half;                      // 8.4 MB
  short* wtb = vtb + half;                      // 2.1 MB
  char* pbase = (char*)(wtb + (size_t)D_ * D_);
  const size_t opart_b = (size_t)NP_ * 1024 * 4;  // per split: 8.4 MB
  const size_t l_b = (size_t)NP_ * 32 * 4;        // per split: 256 KB
  const size_t base_b = (size_t)pbase - (size_t)ws;

  cvt_bf16_kernel<<<half / 2048, 256, 0, stream>>>(k, kbf);
  cvt_vt_kernel<<<B_ * H_ * (S_ / 64), 256, 0, stream>>>(v, vtb);
  cvt_wt_kernel<<<(D_ / 64) * (D_ / 64), 256, 0, stream>>>(W, wtb);

  if (ws_size >= base_b + 2 * (opart_b + l_b)) {
    uint32* Opart = (uint32*)pbase;
    float* Lsum = (float*)(pbase + 2 * opart_b);
    attn_kernel<2><<<2048, 128, 0, stream>>>(q, kbf, vtb, Opart, Lsum, residual, out);
    proj_kernel<2><<<dim3((B_ * S_) / 64, D_ / 128), 256, 0, stream>>>(
        Opart, Lsum, wtb, bO, out + half);
  } else {
    uint32* Opart = (uint32*)pbase;
    float* Lsum = (float*)(pbase + opart_b);
    attn_kernel<1><<<1024, 128, 0, stream>>>(q, kbf, vtb, Opart, Lsum, residual, out);
    proj_kernel<1><<<dim3((B_ * S_) / 64, D_ / 128), 256, 0, stream>>>(
        Opart, Lsum, wtb, bO, out + half);
  }
}